// Round 6
// baseline (1242.455 us; speedup 1.0000x reference)
//
#include <hip/hip_runtime.h>
#include <hip/hip_bf16.h>

#define N_NODES 50000
#define N_EDGES 800000
#define N_RELS 65
#define DIM 64
#define N_GRAPHS 512

#define SORT_BLOCKS 1024
#define CHUNK ((N_EDGES + SORT_BLOCKS - 1) / SORT_BLOCKS)  // 782

#define DCHUNK 64
#define NCHUNKS ((N_NODES + DCHUNK - 1) / DCHUNK)          // 782
#define HPAD 1024                                           // padded bin space
#define MAXCH 2048                                          // max edges per dst-chunk

typedef __attribute__((ext_vector_type(8))) short short8;
typedef __attribute__((ext_vector_type(4))) float f32x4;

// ================= K1 prep: h-convert + chunk-hist + W transpose + zero flag =================

__global__ __launch_bounds__(256) void prep_kernel(
    const float* __restrict__ x, const int* __restrict__ dst,
    __hip_bfloat16* __restrict__ y, int* __restrict__ blk_hist1,
    const float* __restrict__ W1, const float* __restrict__ W2,
    const float* __restrict__ W3,
    __hip_bfloat16* __restrict__ Wt1, __hip_bfloat16* __restrict__ Wt2,
    __hip_bfloat16* __restrict__ Wt3,
    int* __restrict__ done_flags) {
    __shared__ int chist[HPAD];
    __shared__ float tile[64][65];
    int t = threadIdx.x, b = blockIdx.x;
    int gtid = b * 256 + t;

    if (gtid == 0) done_flags[0] = 0;

    for (int i = t; i < HPAD; i += 256) chist[i] = 0;
    __syncthreads();

    // per-block dst-chunk histogram
    int lo = b * CHUNK;
    int hi = lo + CHUNK; if (hi > N_EDGES) hi = N_EDGES;
    for (int i = lo + t; i < hi; i += 256)
        atomicAdd(&chist[dst[i] >> 6], 1);

    // grid-stride h conversion (f32 -> bf16, vectorized)
    for (int i = gtid; i < (N_NODES * DIM) / 4; i += SORT_BLOCKS * 256) {
        float4 v = *(const float4*)(x + (size_t)i * 4);
        unsigned short us[4];
        us[0] = __hip_bfloat16_raw(__float2bfloat16(v.x)).x;
        us[1] = __hip_bfloat16_raw(__float2bfloat16(v.y)).x;
        us[2] = __hip_bfloat16_raw(__float2bfloat16(v.z)).x;
        us[3] = __hip_bfloat16_raw(__float2bfloat16(v.w)).x;
        *(ushort4*)(y + (size_t)i * 4) = *(const ushort4*)us;
    }

    // W transpose+convert: blocks 0..194 (LDS-tiled, coalesced both sides)
    if (b < 3 * N_RELS) {
        int which = b / N_RELS, r = b - which * N_RELS;
        const float* W = (which == 0) ? W1 : (which == 1) ? W2 : W3;
        __hip_bfloat16* Wt = (which == 0) ? Wt1 : (which == 1) ? Wt2 : Wt3;
        for (int i = t; i < 4096; i += 256) {
            int row = i >> 6, col = i & 63;
            tile[row][col] = W[(size_t)r * 4096 + i];
        }
        __syncthreads();
        for (int i = t; i < 4096; i += 256) {
            int row = i >> 6, col = i & 63;
            Wt[(size_t)r * 4096 + i] = __float2bfloat16(tile[col][row]);
        }
    }

    __syncthreads();
    for (int i = t; i < HPAD; i += 256)
        blk_hist1[(size_t)b * HPAD + i] = chist[i];
}

// ================= K2 chunkscan: per-chunk block offsets; last block: chunk_ptr + g_ptr =================

__global__ __launch_bounds__(256) void chunkscan_kernel(
    const int* __restrict__ blk_hist1, int* __restrict__ blk_off1,
    int* __restrict__ chunk_tot, int* __restrict__ chunk_ptr,
    const int* __restrict__ gid, int* __restrict__ g_ptr, int* __restrict__ cnt_g,
    int* __restrict__ done) {
    __shared__ int wsum[4];
    __shared__ int is_last;
    int r = blockIdx.x;              // bin (dst-chunk) id, 0..NCHUNKS-1
    int t = threadIdx.x;
    int w = t >> 6, lane = t & 63;

    int vals[4];
    #pragma unroll
    for (int j = 0; j < 4; ++j)
        vals[j] = blk_hist1[(size_t)(t * 4 + j) * HPAD + r];
    int s = vals[0] + vals[1] + vals[2] + vals[3];
    int x = s;
    #pragma unroll
    for (int off = 1; off < 64; off <<= 1) {
        int y = __shfl_up(x, off);
        if (lane >= off) x += y;
    }
    if (lane == 63) wsum[w] = x;
    __syncthreads();
    int base = 0;
    for (int i = 0; i < w; ++i) base += wsum[i];
    int run = base + x - s;
    #pragma unroll
    for (int j = 0; j < 4; ++j) {
        blk_off1[(size_t)(t * 4 + j) * HPAD + r] = run;
        run += vals[j];
    }

    if (t == 255) {
        __hip_atomic_store(&chunk_tot[r], base + x, __ATOMIC_RELAXED,
                           __HIP_MEMORY_SCOPE_AGENT);
        __threadfence();
        int ticket = atomicAdd(done, 1);
        is_last = (ticket == NCHUNKS - 1) ? 1 : 0;
    }
    __syncthreads();

    if (is_last) {
        // parallel scan of chunk_tot -> chunk_ptr
        int v2[4];
        #pragma unroll
        for (int j = 0; j < 4; ++j) {
            int idx = t * 4 + j;
            v2[j] = (idx < NCHUNKS)
                        ? __hip_atomic_load(&chunk_tot[idx], __ATOMIC_RELAXED,
                                            __HIP_MEMORY_SCOPE_AGENT)
                        : 0;
        }
        int s2 = v2[0] + v2[1] + v2[2] + v2[3];
        int x2 = s2;
        #pragma unroll
        for (int off = 1; off < 64; off <<= 1) {
            int y = __shfl_up(x2, off);
            if (lane >= off) x2 += y;
        }
        __syncthreads();
        if (lane == 63) wsum[w] = x2;
        __syncthreads();
        int base2 = 0;
        for (int i = 0; i < w; ++i) base2 += wsum[i];
        int run2 = base2 + x2 - s2;
        #pragma unroll
        for (int j = 0; j < 4; ++j) {
            int idx = t * 4 + j;
            if (idx < NCHUNKS) chunk_ptr[idx] = run2;
            else chunk_ptr[idx] = N_EDGES;      // pad bins
            run2 += v2[j];
            if (idx == NCHUNKS - 1) chunk_ptr[NCHUNKS] = run2;
        }
        // graph segments via binary search (graph_ids sorted)
        for (int g = t; g < N_GRAPHS; g += 256) {
            int lo2 = 0, hi2 = N_NODES;
            while (lo2 < hi2) { int m = (lo2 + hi2) >> 1; if (gid[m] < g) lo2 = m + 1; else hi2 = m; }
            int a2 = lo2;
            lo2 = 0; hi2 = N_NODES;
            int g1 = g + 1;
            while (lo2 < hi2) { int m = (lo2 + hi2) >> 1; if (gid[m] < g1) lo2 = m + 1; else hi2 = m; }
            g_ptr[g] = a2;
            cnt_g[g] = lo2 - a2;
        }
    }
}

// ================= K3 scatterc: LDS-staged counting sort by dst-chunk (no global atomics) ===========
// record: src(16b) | dst_local(6b) | rel(7b)

__global__ __launch_bounds__(256) void scatterc_kernel(
    const int* __restrict__ et, const int* __restrict__ src,
    const int* __restrict__ dst, const int* __restrict__ blk_hist1,
    const int* __restrict__ blk_off1, const int* __restrict__ chunk_ptr,
    unsigned* __restrict__ epk2) {
    __shared__ int loff[HPAD];
    __shared__ int lcur[HPAD];
    __shared__ int gbase[HPAD];
    __shared__ unsigned srec[CHUNK];
    __shared__ unsigned short sbin[CHUNK];
    __shared__ int wsum[4];
    int t = threadIdx.x, b = blockIdx.x;
    int w = t >> 6, lane = t & 63;

    int4 hv = *(const int4*)(blk_hist1 + (size_t)b * HPAD + t * 4);
    int4 ov = *(const int4*)(blk_off1 + (size_t)b * HPAD + t * 4);
    int4 cp = *(const int4*)(chunk_ptr + t * 4);
    int vals[4] = {hv.x, hv.y, hv.z, hv.w};
    int offs[4] = {ov.x, ov.y, ov.z, ov.w};
    int cps[4]  = {cp.x, cp.y, cp.z, cp.w};
    int s = vals[0] + vals[1] + vals[2] + vals[3];
    int x = s;
    #pragma unroll
    for (int off = 1; off < 64; off <<= 1) {
        int y = __shfl_up(x, off);
        if (lane >= off) x += y;
    }
    if (lane == 63) wsum[w] = x;
    __syncthreads();
    int base = 0;
    for (int i = 0; i < w; ++i) base += wsum[i];
    int run = base + x - s;
    #pragma unroll
    for (int j = 0; j < 4; ++j) {
        loff[t * 4 + j] = run;
        lcur[t * 4 + j] = run;
        gbase[t * 4 + j] = cps[j] + offs[j];
        run += vals[j];
    }
    __syncthreads();

    int lo = b * CHUNK;
    int hi = lo + CHUNK; if (hi > N_EDGES) hi = N_EDGES;
    int nloc = hi - lo;

    #pragma unroll
    for (int k = 0; k < 4; ++k) {
        int i = lo + t + k * 256;
        if (i < hi) {
            int d = dst[i];
            int c = d >> 6;
            unsigned rec = (unsigned)src[i] | ((unsigned)(d & 63) << 16) |
                           ((unsigned)et[i] << 22);
            int pl = atomicAdd(&lcur[c], 1);
            srec[pl] = rec;
            sbin[pl] = (unsigned short)c;
        }
    }
    __syncthreads();

    #pragma unroll
    for (int k = 0; k < 4; ++k) {
        int i = t + k * 256;
        if (i < nloc) {
            int c = sbin[i];
            epk2[gbase[c] + i - loff[c]] = srec[i];
        }
    }
}

// ================= K4 chunksort: per-chunk in-LDS 65-bin rel sort + group offsets =================

__global__ __launch_bounds__(256) void chunksort_kernel(
    const unsigned* __restrict__ epk2, const int* __restrict__ chunk_ptr,
    unsigned* __restrict__ efin, int* __restrict__ grpoff) {
    __shared__ unsigned sin[MAXCH];
    __shared__ int h65[N_RELS], off66[N_RELS + 1], cur65[N_RELS];
    int c = blockIdx.x, t = threadIdx.x;
    int e0 = chunk_ptr[c], e1 = chunk_ptr[c + 1];
    int n = e1 - e0;
    if (n > MAXCH) n = MAXCH;   // safety (statistically impossible)

    if (t < N_RELS) h65[t] = 0;
    __syncthreads();
    for (int i = t; i < n; i += 256) {
        unsigned v = epk2[e0 + i];
        sin[i] = v;
        atomicAdd(&h65[v >> 22], 1);
    }
    __syncthreads();
    if (t < 64) {
        int v = h65[t];
        int x = v;
        #pragma unroll
        for (int off = 1; off < 64; off <<= 1) {
            int y = __shfl_up(x, off);
            if (t >= off) x += y;
        }
        off66[t] = x - v;
        if (t == 63) off66[64] = x;
    }
    __syncthreads();
    if (t == 0) off66[65] = off66[64] + h65[64];
    __syncthreads();
    if (t < N_RELS) cur65[t] = off66[t];
    if (t < N_RELS + 1) grpoff[c * 66 + t] = e0 + off66[t];
    __syncthreads();
    for (int i = t; i < n; i += 256) {
        unsigned v = sin[i];
        int r = v >> 22;
        int pos = atomicAdd(&cur65[r], 1);
        efin[e0 + pos] = v;
    }
}

// ================= K5 fused RGCN layer: gather + MFMA + LDS fp32 accumulate + ReLU =================

__global__ __launch_bounds__(256) void layer_kernel(
    const __hip_bfloat16* __restrict__ hb, const __hip_bfloat16* __restrict__ Wt,
    const unsigned* __restrict__ efin, const int* __restrict__ grpoff,
    const float* __restrict__ bias, __hip_bfloat16* __restrict__ hout) {
    __shared__ float acc[64 * 68];
    __shared__ int goff[N_RELS + 1];
    int c = blockIdx.x, t = threadIdx.x;
    int w = t >> 6, lane = t & 63;
    int quad = lane >> 4, m16 = lane & 15;

    for (int i = t; i < 64 * 68; i += 256) acc[i] = 0.f;
    if (t < N_RELS + 1) goff[t] = grpoff[c * 66 + t];
    __syncthreads();

    for (int r = w; r < N_RELS; r += 4) {
        int g0 = goff[r], g1 = goff[r + 1];
        if (g0 >= g1) continue;

        // B fragments, 4-col interleave (tile j -> true col 4*m16+j), identical
        // layout to the proven msg kernel.
        const __hip_bfloat16* Wr = Wt + (size_t)r * (DIM * DIM);
        short8 bf00 = *(const short8*)(Wr + (4 * m16)     * DIM + quad * 8);
        short8 bf01 = *(const short8*)(Wr + (4 * m16 + 1) * DIM + quad * 8);
        short8 bf02 = *(const short8*)(Wr + (4 * m16 + 2) * DIM + quad * 8);
        short8 bf03 = *(const short8*)(Wr + (4 * m16 + 3) * DIM + quad * 8);
        short8 bf10 = *(const short8*)(Wr + (4 * m16)     * DIM + 32 + quad * 8);
        short8 bf11 = *(const short8*)(Wr + (4 * m16 + 1) * DIM + 32 + quad * 8);
        short8 bf12 = *(const short8*)(Wr + (4 * m16 + 2) * DIM + 32 + quad * 8);
        short8 bf13 = *(const short8*)(Wr + (4 * m16 + 3) * DIM + 32 + quad * 8);

        for (int tb = g0; tb < g1; tb += 16) {
            int e = tb + m16;
            int ec = (e < g1) ? e : g1 - 1;
            unsigned rec = efin[ec];
            int s = rec & 0xFFFF;
            const __hip_bfloat16* hp = hb + (size_t)s * DIM + quad * 8;
            short8 a0 = *(const short8*)hp;
            short8 a1 = *(const short8*)(hp + 32);

            f32x4 c0 = {0.f, 0.f, 0.f, 0.f}, c1 = c0, c2 = c0, c3 = c0;
            c0 = __builtin_amdgcn_mfma_f32_16x16x32_bf16(a0, bf00, c0, 0, 0, 0);
            c1 = __builtin_amdgcn_mfma_f32_16x16x32_bf16(a0, bf01, c1, 0, 0, 0);
            c2 = __builtin_amdgcn_mfma_f32_16x16x32_bf16(a0, bf02, c2, 0, 0, 0);
            c3 = __builtin_amdgcn_mfma_f32_16x16x32_bf16(a0, bf03, c3, 0, 0, 0);
            c0 = __builtin_amdgcn_mfma_f32_16x16x32_bf16(a1, bf10, c0, 0, 0, 0);
            c1 = __builtin_amdgcn_mfma_f32_16x16x32_bf16(a1, bf11, c1, 0, 0, 0);
            c2 = __builtin_amdgcn_mfma_f32_16x16x32_bf16(a1, bf12, c2, 0, 0, 0);
            c3 = __builtin_amdgcn_mfma_f32_16x16x32_bf16(a1, bf13, c3, 0, 0, 0);

            int rows = g1 - tb; if (rows > 16) rows = 16;
            #pragma unroll
            for (int g = 0; g < 4; ++g) {
                int row = quad * 4 + g;
                unsigned rr = (unsigned)__shfl((int)rec, row);
                if (row < rows) {
                    int dl = (rr >> 16) & 63;
                    float* ap = &acc[dl * 68 + 4 * m16];
                    atomicAdd(ap + 0, c0[g]);
                    atomicAdd(ap + 1, c1[g]);
                    atomicAdd(ap + 2, c2[g]);
                    atomicAdd(ap + 3, c3[g]);
                }
            }
        }
    }
    __syncthreads();

    // epilogue: bias + ReLU + bf16, linear write
    int dl = t >> 2, q4 = (t & 3) * 16;
    int d = c * DCHUNK + dl;
    if (d < N_NODES) {
        unsigned short us[16];
        #pragma unroll
        for (int j = 0; j < 16; ++j) {
            float v = acc[dl * 68 + q4 + j] + bias[q4 + j];
            us[j] = __hip_bfloat16_raw(__float2bfloat16(v > 0.f ? v : 0.f)).x;
        }
        __hip_bfloat16* hp = hout + (size_t)d * DIM + q4;
        *(uint4*)hp = *(const uint4*)&us[0];
        *(uint4*)(hp + 8) = *(const uint4*)&us[8];
    }
}

// ================= fused pool + FC x3 + prediction head =================

__global__ __launch_bounds__(256) void poolfc_kernel(
    const __hip_bfloat16* __restrict__ h, const int* __restrict__ g_ptr,
    const int* __restrict__ cnt_g,
    const float* __restrict__ W1, const float* __restrict__ b1,
    const float* __restrict__ W2, const float* __restrict__ b2,
    const float* __restrict__ W3, const float* __restrict__ b3,
    const float* __restrict__ pW, const float* __restrict__ pb,
    float* __restrict__ out) {
    int wave = blockIdx.x * 4 + (threadIdx.x >> 6);
    int lane = threadIdx.x & 63;
    if (wave >= N_GRAPHS) return;
    int j0 = g_ptr[wave];
    int n  = cnt_g[wave];
    int rgrp = lane >> 3, dgrp = lane & 7;

    float a[8] = {0.f, 0.f, 0.f, 0.f, 0.f, 0.f, 0.f, 0.f};
    for (int jj = 0; jj < n; jj += 8) {
        int row = jj + rgrp;
        if (row < n) {
            uint4 d = *(const uint4*)(h + (size_t)(j0 + row) * DIM + dgrp * 8);
            a[0] += __uint_as_float(d.x << 16);
            a[1] += __uint_as_float(d.x & 0xffff0000u);
            a[2] += __uint_as_float(d.y << 16);
            a[3] += __uint_as_float(d.y & 0xffff0000u);
            a[4] += __uint_as_float(d.z << 16);
            a[5] += __uint_as_float(d.z & 0xffff0000u);
            a[6] += __uint_as_float(d.w << 16);
            a[7] += __uint_as_float(d.w & 0xffff0000u);
        }
    }
    #pragma unroll
    for (int i = 0; i < 8; ++i) {
        a[i] += __shfl_xor(a[i], 8);
        a[i] += __shfl_xor(a[i], 16);
        a[i] += __shfl_xor(a[i], 32);
    }
    float v;
    {
        float acc = b1[lane];
        #pragma unroll
        for (int o = 0; o < 8; ++o)
            #pragma unroll
            for (int q = 0; q < 8; ++q)
                acc += __shfl(a[o], q) * W1[(q * 8 + o) * DIM + lane];
        v = acc > 0.f ? acc : 0.f;
    }
    {
        float acc = b2[lane];
        #pragma unroll
        for (int d = 0; d < DIM; ++d)
            acc += __shfl(v, d) * W2[d * DIM + lane];
        v = acc > 0.f ? acc : 0.f;
    }
    {
        float acc = b3[lane];
        #pragma unroll
        for (int d = 0; d < DIM; ++d)
            acc += __shfl(v, d) * W3[d * DIM + lane];
        v = acc > 0.f ? acc : 0.f;
    }
    float p0 = v * pW[lane * 2 + 0];
    float p1 = v * pW[lane * 2 + 1];
    #pragma unroll
    for (int off = 32; off > 0; off >>= 1) {
        p0 += __shfl_down(p0, off);
        p1 += __shfl_down(p1, off);
    }
    if (lane == 0) {
        out[wave * 2 + 0] = p0 + pb[0];
        out[wave * 2 + 1] = p1 + pb[1];
    }
}

// ================= launch =================

extern "C" void kernel_launch(void* const* d_in, const int* in_sizes, int n_in,
                              void* d_out, int out_size, void* d_ws, size_t ws_size,
                              hipStream_t stream) {
    const float* node_feats = (const float*)d_in[0];
    const int*   etypes     = (const int*)d_in[1];
    const int*   src        = (const int*)d_in[2];
    const int*   dst        = (const int*)d_in[3];
    const int*   graph_ids  = (const int*)d_in[4];
    const float* W1 = (const float*)d_in[5];
    const float* b1 = (const float*)d_in[6];
    const float* W2 = (const float*)d_in[7];
    const float* b2 = (const float*)d_in[8];
    const float* W3 = (const float*)d_in[9];
    const float* b3 = (const float*)d_in[10];
    const float* fcW1 = (const float*)d_in[11];
    const float* fcb1 = (const float*)d_in[12];
    const float* fcW2 = (const float*)d_in[13];
    const float* fcb2 = (const float*)d_in[14];
    const float* fcW3 = (const float*)d_in[15];
    const float* fcb3 = (const float*)d_in[16];
    const float* pW = (const float*)d_in[17];
    const float* pb = (const float*)d_in[18];
    float* out = (float*)d_out;

    // workspace carve-up (256B aligned)
    char* p = (char*)d_ws;
    auto alloc = [&](size_t bytes) -> void* {
        void* r = (void*)p;
        p += (bytes + 255) & ~(size_t)255;
        return r;
    };
    int* blk_hist1 = (int*)alloc((size_t)SORT_BLOCKS * HPAD * sizeof(int));   // 4MB
    int* blk_off1  = (int*)alloc((size_t)SORT_BLOCKS * HPAD * sizeof(int));   // 4MB
    int* chunk_tot = (int*)alloc(HPAD * sizeof(int));
    int* chunk_ptr = (int*)alloc((HPAD + 1) * sizeof(int));
    unsigned* epk2 = (unsigned*)alloc((size_t)N_EDGES * sizeof(unsigned));    // 3.2MB
    unsigned* efin = (unsigned*)alloc((size_t)N_EDGES * sizeof(unsigned));    // 3.2MB
    int* grpoff    = (int*)alloc((size_t)NCHUNKS * 66 * sizeof(int));         // 206KB
    int* cnt_g     = (int*)alloc(N_GRAPHS * sizeof(int));
    int* g_ptr     = (int*)alloc(N_GRAPHS * sizeof(int));
    int* done_flags= (int*)alloc(2 * sizeof(int));
    __hip_bfloat16* hb0 = (__hip_bfloat16*)alloc((size_t)N_NODES * DIM * sizeof(__hip_bfloat16));
    __hip_bfloat16* hb1 = (__hip_bfloat16*)alloc((size_t)N_NODES * DIM * sizeof(__hip_bfloat16));
    __hip_bfloat16* Wt1 = (__hip_bfloat16*)alloc((size_t)N_RELS * DIM * DIM * sizeof(__hip_bfloat16));
    __hip_bfloat16* Wt2 = (__hip_bfloat16*)alloc((size_t)N_RELS * DIM * DIM * sizeof(__hip_bfloat16));
    __hip_bfloat16* Wt3 = (__hip_bfloat16*)alloc((size_t)N_RELS * DIM * DIM * sizeof(__hip_bfloat16));

    // ---- prep + sort (4 dispatches) ----
    prep_kernel<<<SORT_BLOCKS, 256, 0, stream>>>(node_feats, dst, hb0, blk_hist1,
                                                 W1, W2, W3, Wt1, Wt2, Wt3, done_flags);
    chunkscan_kernel<<<NCHUNKS, 256, 0, stream>>>(blk_hist1, blk_off1, chunk_tot,
                                                  chunk_ptr, graph_ids, g_ptr, cnt_g,
                                                  &done_flags[0]);
    scatterc_kernel<<<SORT_BLOCKS, 256, 0, stream>>>(etypes, src, dst, blk_hist1,
                                                     blk_off1, chunk_ptr, epk2);
    chunksort_kernel<<<NCHUNKS, 256, 0, stream>>>(epk2, chunk_ptr, efin, grpoff);

    // ---- 3 fused RGCN layers (messages never hit memory) ----
    layer_kernel<<<NCHUNKS, 256, 0, stream>>>(hb0, Wt1, efin, grpoff, b1, hb1);
    layer_kernel<<<NCHUNKS, 256, 0, stream>>>(hb1, Wt2, efin, grpoff, b2, hb0);
    layer_kernel<<<NCHUNKS, 256, 0, stream>>>(hb0, Wt3, efin, grpoff, b3, hb1);

    // ---- fused pool + FC head ----
    poolfc_kernel<<<(N_GRAPHS + 3) / 4, 256, 0, stream>>>(hb1, g_ptr, cnt_g,
                                                          fcW1, fcb1, fcW2, fcb2,
                                                          fcW3, fcb3, pW, pb, out);
}

// Round 7
// 513.788 us; speedup vs baseline: 2.4182x; 2.4182x over previous
//
#include <hip/hip_runtime.h>
#include <hip/hip_bf16.h>

#define N_NODES 50000
#define N_EDGES 800000
#define N_RELS 65
#define DIM 64
#define N_GRAPHS 512

#define SORT_BLOCKS 1024
#define CHUNK ((N_EDGES + SORT_BLOCKS - 1) / SORT_BLOCKS)  // 782

#define DCHUNK 64
#define NCHUNKS ((N_NODES + DCHUNK - 1) / DCHUNK)          // 782
#define HPAD 1024                                           // padded bin space
#define MAXCH 2048                                          // max edges per dst-chunk

typedef __attribute__((ext_vector_type(8))) short short8;
typedef __attribute__((ext_vector_type(4))) float f32x4;

// ================= K1 prep: h-convert + chunk-hist + W transpose + zero flag =================

__global__ __launch_bounds__(256) void prep_kernel(
    const float* __restrict__ x, const int* __restrict__ dst,
    __hip_bfloat16* __restrict__ y, int* __restrict__ blk_hist1,
    const float* __restrict__ W1, const float* __restrict__ W2,
    const float* __restrict__ W3,
    __hip_bfloat16* __restrict__ Wt1, __hip_bfloat16* __restrict__ Wt2,
    __hip_bfloat16* __restrict__ Wt3,
    int* __restrict__ done_flags) {
    __shared__ int chist[HPAD];
    __shared__ float tile[64][65];
    int t = threadIdx.x, b = blockIdx.x;
    int gtid = b * 256 + t;

    if (gtid == 0) done_flags[0] = 0;

    for (int i = t; i < HPAD; i += 256) chist[i] = 0;
    __syncthreads();

    // per-block dst-chunk histogram
    int lo = b * CHUNK;
    int hi = lo + CHUNK; if (hi > N_EDGES) hi = N_EDGES;
    for (int i = lo + t; i < hi; i += 256)
        atomicAdd(&chist[dst[i] >> 6], 1);

    // grid-stride h conversion (f32 -> bf16, vectorized)
    for (int i = gtid; i < (N_NODES * DIM) / 4; i += SORT_BLOCKS * 256) {
        float4 v = *(const float4*)(x + (size_t)i * 4);
        unsigned short us[4];
        us[0] = __hip_bfloat16_raw(__float2bfloat16(v.x)).x;
        us[1] = __hip_bfloat16_raw(__float2bfloat16(v.y)).x;
        us[2] = __hip_bfloat16_raw(__float2bfloat16(v.z)).x;
        us[3] = __hip_bfloat16_raw(__float2bfloat16(v.w)).x;
        *(ushort4*)(y + (size_t)i * 4) = *(const ushort4*)us;
    }

    // W transpose+convert: blocks 0..194 (LDS-tiled, coalesced both sides)
    if (b < 3 * N_RELS) {
        int which = b / N_RELS, r = b - which * N_RELS;
        const float* W = (which == 0) ? W1 : (which == 1) ? W2 : W3;
        __hip_bfloat16* Wt = (which == 0) ? Wt1 : (which == 1) ? Wt2 : Wt3;
        for (int i = t; i < 4096; i += 256) {
            int row = i >> 6, col = i & 63;
            tile[row][col] = W[(size_t)r * 4096 + i];
        }
        __syncthreads();
        for (int i = t; i < 4096; i += 256) {
            int row = i >> 6, col = i & 63;
            Wt[(size_t)r * 4096 + i] = __float2bfloat16(tile[col][row]);
        }
    }

    __syncthreads();
    for (int i = t; i < HPAD; i += 256)
        blk_hist1[(size_t)b * HPAD + i] = chist[i];
}

// ================= K2 chunkscan: per-chunk block offsets; last block: chunk_ptr + g_ptr =================

__global__ __launch_bounds__(256) void chunkscan_kernel(
    const int* __restrict__ blk_hist1, int* __restrict__ blk_off1,
    int* __restrict__ chunk_tot, int* __restrict__ chunk_ptr,
    const int* __restrict__ gid, int* __restrict__ g_ptr, int* __restrict__ cnt_g,
    int* __restrict__ done) {
    __shared__ int wsum[4];
    __shared__ int is_last;
    int r = blockIdx.x;              // bin (dst-chunk) id, 0..NCHUNKS-1
    int t = threadIdx.x;
    int w = t >> 6, lane = t & 63;

    int vals[4];
    #pragma unroll
    for (int j = 0; j < 4; ++j)
        vals[j] = blk_hist1[(size_t)(t * 4 + j) * HPAD + r];
    int s = vals[0] + vals[1] + vals[2] + vals[3];
    int x = s;
    #pragma unroll
    for (int off = 1; off < 64; off <<= 1) {
        int y = __shfl_up(x, off);
        if (lane >= off) x += y;
    }
    if (lane == 63) wsum[w] = x;
    __syncthreads();
    int base = 0;
    for (int i = 0; i < w; ++i) base += wsum[i];
    int run = base + x - s;
    #pragma unroll
    for (int j = 0; j < 4; ++j) {
        blk_off1[(size_t)(t * 4 + j) * HPAD + r] = run;
        run += vals[j];
    }

    if (t == 255) {
        __hip_atomic_store(&chunk_tot[r], base + x, __ATOMIC_RELAXED,
                           __HIP_MEMORY_SCOPE_AGENT);
        __threadfence();
        int ticket = atomicAdd(done, 1);
        is_last = (ticket == NCHUNKS - 1) ? 1 : 0;
    }
    __syncthreads();

    if (is_last) {
        // parallel scan of chunk_tot -> chunk_ptr
        int v2[4];
        #pragma unroll
        for (int j = 0; j < 4; ++j) {
            int idx = t * 4 + j;
            v2[j] = (idx < NCHUNKS)
                        ? __hip_atomic_load(&chunk_tot[idx], __ATOMIC_RELAXED,
                                            __HIP_MEMORY_SCOPE_AGENT)
                        : 0;
        }
        int s2 = v2[0] + v2[1] + v2[2] + v2[3];
        int x2 = s2;
        #pragma unroll
        for (int off = 1; off < 64; off <<= 1) {
            int y = __shfl_up(x2, off);
            if (lane >= off) x2 += y;
        }
        __syncthreads();
        if (lane == 63) wsum[w] = x2;
        __syncthreads();
        int base2 = 0;
        for (int i = 0; i < w; ++i) base2 += wsum[i];
        int run2 = base2 + x2 - s2;
        #pragma unroll
        for (int j = 0; j < 4; ++j) {
            int idx = t * 4 + j;
            if (idx < NCHUNKS) chunk_ptr[idx] = run2;
            else chunk_ptr[idx] = N_EDGES;      // pad bins
            run2 += v2[j];
            if (idx == NCHUNKS - 1) chunk_ptr[NCHUNKS] = run2;
        }
        // graph segments via binary search (graph_ids sorted)
        for (int g = t; g < N_GRAPHS; g += 256) {
            int lo2 = 0, hi2 = N_NODES;
            while (lo2 < hi2) { int m = (lo2 + hi2) >> 1; if (gid[m] < g) lo2 = m + 1; else hi2 = m; }
            int a2 = lo2;
            lo2 = 0; hi2 = N_NODES;
            int g1 = g + 1;
            while (lo2 < hi2) { int m = (lo2 + hi2) >> 1; if (gid[m] < g1) lo2 = m + 1; else hi2 = m; }
            g_ptr[g] = a2;
            cnt_g[g] = lo2 - a2;
        }
    }
}

// ================= K3 scatterc: LDS-staged counting sort by dst-chunk (no global atomics) ===========
// record: src(16b) | dst_local(6b) | rel(7b)

__global__ __launch_bounds__(256) void scatterc_kernel(
    const int* __restrict__ et, const int* __restrict__ src,
    const int* __restrict__ dst, const int* __restrict__ blk_hist1,
    const int* __restrict__ blk_off1, const int* __restrict__ chunk_ptr,
    unsigned* __restrict__ epk2) {
    __shared__ int loff[HPAD];
    __shared__ int lcur[HPAD];
    __shared__ int gbase[HPAD];
    __shared__ unsigned srec[CHUNK];
    __shared__ unsigned short sbin[CHUNK];
    __shared__ int wsum[4];
    int t = threadIdx.x, b = blockIdx.x;
    int w = t >> 6, lane = t & 63;

    int4 hv = *(const int4*)(blk_hist1 + (size_t)b * HPAD + t * 4);
    int4 ov = *(const int4*)(blk_off1 + (size_t)b * HPAD + t * 4);
    int4 cp = *(const int4*)(chunk_ptr + t * 4);
    int vals[4] = {hv.x, hv.y, hv.z, hv.w};
    int offs[4] = {ov.x, ov.y, ov.z, ov.w};
    int cps[4]  = {cp.x, cp.y, cp.z, cp.w};
    int s = vals[0] + vals[1] + vals[2] + vals[3];
    int x = s;
    #pragma unroll
    for (int off = 1; off < 64; off <<= 1) {
        int y = __shfl_up(x, off);
        if (lane >= off) x += y;
    }
    if (lane == 63) wsum[w] = x;
    __syncthreads();
    int base = 0;
    for (int i = 0; i < w; ++i) base += wsum[i];
    int run = base + x - s;
    #pragma unroll
    for (int j = 0; j < 4; ++j) {
        loff[t * 4 + j] = run;
        lcur[t * 4 + j] = run;
        gbase[t * 4 + j] = cps[j] + offs[j];
        run += vals[j];
    }
    __syncthreads();

    int lo = b * CHUNK;
    int hi = lo + CHUNK; if (hi > N_EDGES) hi = N_EDGES;
    int nloc = hi - lo;

    #pragma unroll
    for (int k = 0; k < 4; ++k) {
        int i = lo + t + k * 256;
        if (i < hi) {
            int d = dst[i];
            int c = d >> 6;
            unsigned rec = (unsigned)src[i] | ((unsigned)(d & 63) << 16) |
                           ((unsigned)et[i] << 22);
            int pl = atomicAdd(&lcur[c], 1);
            srec[pl] = rec;
            sbin[pl] = (unsigned short)c;
        }
    }
    __syncthreads();

    #pragma unroll
    for (int k = 0; k < 4; ++k) {
        int i = t + k * 256;
        if (i < nloc) {
            int c = sbin[i];
            epk2[gbase[c] + i - loff[c]] = srec[i];
        }
    }
}

// ================= K4 chunksort: per-chunk in-LDS 65-bin rel sort + group offsets =================

__global__ __launch_bounds__(256) void chunksort_kernel(
    const unsigned* __restrict__ epk2, const int* __restrict__ chunk_ptr,
    unsigned* __restrict__ efin, int* __restrict__ grpoff) {
    __shared__ unsigned sin[MAXCH];
    __shared__ int h65[N_RELS], off66[N_RELS + 1], cur65[N_RELS];
    int c = blockIdx.x, t = threadIdx.x;
    int e0 = chunk_ptr[c], e1 = chunk_ptr[c + 1];
    int n = e1 - e0;
    if (n > MAXCH) n = MAXCH;   // safety (statistically impossible)

    if (t < N_RELS) h65[t] = 0;
    __syncthreads();
    for (int i = t; i < n; i += 256) {
        unsigned v = epk2[e0 + i];
        sin[i] = v;
        atomicAdd(&h65[v >> 22], 1);
    }
    __syncthreads();
    if (t < 64) {
        int v = h65[t];
        int x = v;
        #pragma unroll
        for (int off = 1; off < 64; off <<= 1) {
            int y = __shfl_up(x, off);
            if (t >= off) x += y;
        }
        off66[t] = x - v;
        if (t == 63) off66[64] = x;
    }
    __syncthreads();
    if (t == 0) off66[65] = off66[64] + h65[64];
    __syncthreads();
    if (t < N_RELS) cur65[t] = off66[t];
    if (t < N_RELS + 1) grpoff[c * 66 + t] = e0 + off66[t];
    __syncthreads();
    for (int i = t; i < n; i += 256) {
        unsigned v = sin[i];
        int r = v >> 22;
        int pos = atomicAdd(&cur65[r], 1);
        efin[e0 + pos] = v;
    }
}

// ================= K5 fused RGCN layer: double-MFMA (project + one-hot scatter) =================
// Per 32-edge tile: M = h_src * W_r (16x16x32 MFMA, natural col layout), then
// Acc += Onehot^T * bf16(M) (16 more MFMAs). Chunk accumulator (64x64 fp32)
// lives in MFMA C registers across all tiles/groups. ZERO LDS ops in hot loop
// (R6's 355us was the per-edge LDS atomicAdd pipe, ~200k atomic lane-ops/CU).

__global__ __launch_bounds__(256) void layer_kernel(
    const __hip_bfloat16* __restrict__ hb, const __hip_bfloat16* __restrict__ Wt,
    const unsigned* __restrict__ efin, const int* __restrict__ grpoff,
    const float* __restrict__ bias, __hip_bfloat16* __restrict__ hout) {
    __shared__ float buf[64 * 68];
    __shared__ int goff[N_RELS + 1];
    int c = blockIdx.x, t = threadIdx.x;
    int w = t >> 6, lane = t & 63;
    int quad = lane >> 4, m16 = lane & 15;

    if (t < N_RELS + 1) goff[t] = grpoff[c * 66 + t];
    __syncthreads();

    // chunk accumulator: Acc[rb*16 + quad*4+g][n*16 + m16] in acc[rb][n][g]
    f32x4 acc[4][4];
    #pragma unroll
    for (int rb = 0; rb < 4; ++rb)
        #pragma unroll
        for (int n = 0; n < 4; ++n)
            acc[rb][n] = (f32x4){0.f, 0.f, 0.f, 0.f};

    for (int r = w; r < N_RELS; r += 4) {
        int g0 = goff[r], g1 = goff[r + 1];
        if (g0 >= g1) continue;

        // W B-fragments, NATURAL layout: tile n = output cols n*16..n*16+15.
        const __hip_bfloat16* Wr = Wt + (size_t)r * (DIM * DIM);
        short8 wf0[4], wf1[4];
        #pragma unroll
        for (int n = 0; n < 4; ++n) {
            wf0[n] = *(const short8*)(Wr + (n * 16 + m16) * DIM + quad * 8);
            wf1[n] = *(const short8*)(Wr + (n * 16 + m16) * DIM + 32 + quad * 8);
        }

        for (int tb = g0; tb < g1; tb += 32) {
            int rows = g1 - tb; if (rows > 32) rows = 32;
            int ei = tb + (lane & 31);
            unsigned rec = efin[ei < g1 ? ei : g1 - 1];

            // ---- projection: M[e][col], two 16-edge subtiles ----
            f32x4 cA[4], cB[4];
            #pragma unroll
            for (int n = 0; n < 4; ++n) {
                cA[n] = (f32x4){0.f, 0.f, 0.f, 0.f};
                cB[n] = (f32x4){0.f, 0.f, 0.f, 0.f};
            }
            {
                int sA = __shfl((int)rec, m16) & 0xFFFF;
                const __hip_bfloat16* hp = hb + (size_t)sA * DIM + quad * 8;
                short8 a0 = *(const short8*)hp;
                short8 a1 = *(const short8*)(hp + 32);
                #pragma unroll
                for (int n = 0; n < 4; ++n) {
                    cA[n] = __builtin_amdgcn_mfma_f32_16x16x32_bf16(a0, wf0[n], cA[n], 0, 0, 0);
                    cA[n] = __builtin_amdgcn_mfma_f32_16x16x32_bf16(a1, wf1[n], cA[n], 0, 0, 0);
                }
            }
            if (rows > 16) {
                int sB = __shfl((int)rec, 16 + m16) & 0xFFFF;
                const __hip_bfloat16* hp = hb + (size_t)sB * DIM + quad * 8;
                short8 a0 = *(const short8*)hp;
                short8 a1 = *(const short8*)(hp + 32);
                #pragma unroll
                for (int n = 0; n < 4; ++n) {
                    cB[n] = __builtin_amdgcn_mfma_f32_16x16x32_bf16(a0, wf0[n], cB[n], 0, 0, 0);
                    cB[n] = __builtin_amdgcn_mfma_f32_16x16x32_bf16(a1, wf1[n], cB[n], 0, 0, 0);
                }
            }

            // ---- one-hot A-fragments: oh[rb][j] = (dl(e)==rb*16+m16 && e valid), e = quad*8+j
            int dl[8];
            #pragma unroll
            for (int j = 0; j < 8; ++j)
                dl[j] = (__shfl((int)rec, quad * 8 + j) >> 16) & 63;
            short8 oh[4];
            #pragma unroll
            for (int rb = 0; rb < 4; ++rb) {
                #pragma unroll
                for (int j = 0; j < 8; ++j) {
                    bool v = (dl[j] == rb * 16 + m16) && (quad * 8 + j < rows);
                    oh[rb][j] = v ? (short)0x3F80 : (short)0;
                }
            }

            // ---- scatter B-fragments: bs[n][j] = bf16(M[e = quad*8+j][n*16+m16])
            // M[e][col] lives at lane ((e&15)>>2)*16 + col_m16, reg c{e>>4}[n][(e&15)&3].
            short8 bs[4];
            #pragma unroll
            for (int n = 0; n < 4; ++n) {
                #pragma unroll
                for (int j = 0; j < 8; ++j) {
                    int srcl = ((quad & 1) * 2 + (j >> 2)) * 16 + m16;
                    float vA = __shfl(cA[n][j & 3], srcl);
                    float vB = __shfl(cB[n][j & 3], srcl);
                    float v = (quad < 2) ? vA : vB;
                    bs[n][j] = (short)__hip_bfloat16_raw(__float2bfloat16(v)).x;
                }
            }

            // ---- scatter: Acc += Onehot^T x M  (16 MFMAs, K=32 edges) ----
            #pragma unroll
            for (int rb = 0; rb < 4; ++rb)
                #pragma unroll
                for (int n = 0; n < 4; ++n)
                    acc[rb][n] = __builtin_amdgcn_mfma_f32_16x16x32_bf16(
                        oh[rb], bs[n], acc[rb][n], 0, 0, 0);
        }
    }

    // ---- merge the 4 waves' register accumulators into LDS (no atomics) ----
    #pragma unroll
    for (int ww = 0; ww < 4; ++ww) {
        if (w == ww) {
            #pragma unroll
            for (int rb = 0; rb < 4; ++rb)
                #pragma unroll
                for (int n = 0; n < 4; ++n)
                    #pragma unroll
                    for (int g = 0; g < 4; ++g) {
                        int row = rb * 16 + quad * 4 + g;
                        int col = n * 16 + m16;
                        if (ww == 0) buf[row * 68 + col] = acc[rb][n][g];
                        else         buf[row * 68 + col] += acc[rb][n][g];
                    }
        }
        __syncthreads();
    }

    // epilogue: bias + ReLU + bf16, linear write
    int dl2 = t >> 2, q4 = (t & 3) * 16;
    int d = c * DCHUNK + dl2;
    if (d < N_NODES) {
        unsigned short us[16];
        #pragma unroll
        for (int j = 0; j < 16; ++j) {
            float v = buf[dl2 * 68 + q4 + j] + bias[q4 + j];
            us[j] = __hip_bfloat16_raw(__float2bfloat16(v > 0.f ? v : 0.f)).x;
        }
        __hip_bfloat16* hp = hout + (size_t)d * DIM + q4;
        *(uint4*)hp = *(const uint4*)&us[0];
        *(uint4*)(hp + 8) = *(const uint4*)&us[8];
    }
}

// ================= fused pool + FC x3 + prediction head =================

__global__ __launch_bounds__(256) void poolfc_kernel(
    const __hip_bfloat16* __restrict__ h, const int* __restrict__ g_ptr,
    const int* __restrict__ cnt_g,
    const float* __restrict__ W1, const float* __restrict__ b1,
    const float* __restrict__ W2, const float* __restrict__ b2,
    const float* __restrict__ W3, const float* __restrict__ b3,
    const float* __restrict__ pW, const float* __restrict__ pb,
    float* __restrict__ out) {
    int wave = blockIdx.x * 4 + (threadIdx.x >> 6);
    int lane = threadIdx.x & 63;
    if (wave >= N_GRAPHS) return;
    int j0 = g_ptr[wave];
    int n  = cnt_g[wave];
    int rgrp = lane >> 3, dgrp = lane & 7;

    float a[8] = {0.f, 0.f, 0.f, 0.f, 0.f, 0.f, 0.f, 0.f};
    for (int jj = 0; jj < n; jj += 8) {
        int row = jj + rgrp;
        if (row < n) {
            uint4 d = *(const uint4*)(h + (size_t)(j0 + row) * DIM + dgrp * 8);
            a[0] += __uint_as_float(d.x << 16);
            a[1] += __uint_as_float(d.x & 0xffff0000u);
            a[2] += __uint_as_float(d.y << 16);
            a[3] += __uint_as_float(d.y & 0xffff0000u);
            a[4] += __uint_as_float(d.z << 16);
            a[5] += __uint_as_float(d.z & 0xffff0000u);
            a[6] += __uint_as_float(d.w << 16);
            a[7] += __uint_as_float(d.w & 0xffff0000u);
        }
    }
    #pragma unroll
    for (int i = 0; i < 8; ++i) {
        a[i] += __shfl_xor(a[i], 8);
        a[i] += __shfl_xor(a[i], 16);
        a[i] += __shfl_xor(a[i], 32);
    }
    float v;
    {
        float acc = b1[lane];
        #pragma unroll
        for (int o = 0; o < 8; ++o)
            #pragma unroll
            for (int q = 0; q < 8; ++q)
                acc += __shfl(a[o], q) * W1[(q * 8 + o) * DIM + lane];
        v = acc > 0.f ? acc : 0.f;
    }
    {
        float acc = b2[lane];
        #pragma unroll
        for (int d = 0; d < DIM; ++d)
            acc += __shfl(v, d) * W2[d * DIM + lane];
        v = acc > 0.f ? acc : 0.f;
    }
    {
        float acc = b3[lane];
        #pragma unroll
        for (int d = 0; d < DIM; ++d)
            acc += __shfl(v, d) * W3[d * DIM + lane];
        v = acc > 0.f ? acc : 0.f;
    }
    float p0 = v * pW[lane * 2 + 0];
    float p1 = v * pW[lane * 2 + 1];
    #pragma unroll
    for (int off = 32; off > 0; off >>= 1) {
        p0 += __shfl_down(p0, off);
        p1 += __shfl_down(p1, off);
    }
    if (lane == 0) {
        out[wave * 2 + 0] = p0 + pb[0];
        out[wave * 2 + 1] = p1 + pb[1];
    }
}

// ================= launch =================

extern "C" void kernel_launch(void* const* d_in, const int* in_sizes, int n_in,
                              void* d_out, int out_size, void* d_ws, size_t ws_size,
                              hipStream_t stream) {
    const float* node_feats = (const float*)d_in[0];
    const int*   etypes     = (const int*)d_in[1];
    const int*   src        = (const int*)d_in[2];
    const int*   dst        = (const int*)d_in[3];
    const int*   graph_ids  = (const int*)d_in[4];
    const float* W1 = (const float*)d_in[5];
    const float* b1 = (const float*)d_in[6];
    const float* W2 = (const float*)d_in[7];
    const float* b2 = (const float*)d_in[8];
    const float* W3 = (const float*)d_in[9];
    const float* b3 = (const float*)d_in[10];
    const float* fcW1 = (const float*)d_in[11];
    const float* fcb1 = (const float*)d_in[12];
    const float* fcW2 = (const float*)d_in[13];
    const float* fcb2 = (const float*)d_in[14];
    const float* fcW3 = (const float*)d_in[15];
    const float* fcb3 = (const float*)d_in[16];
    const float* pW = (const float*)d_in[17];
    const float* pb = (const float*)d_in[18];
    float* out = (float*)d_out;

    // workspace carve-up (256B aligned)
    char* p = (char*)d_ws;
    auto alloc = [&](size_t bytes) -> void* {
        void* r = (void*)p;
        p += (bytes + 255) & ~(size_t)255;
        return r;
    };
    int* blk_hist1 = (int*)alloc((size_t)SORT_BLOCKS * HPAD * sizeof(int));   // 4MB
    int* blk_off1  = (int*)alloc((size_t)SORT_BLOCKS * HPAD * sizeof(int));   // 4MB
    int* chunk_tot = (int*)alloc(HPAD * sizeof(int));
    int* chunk_ptr = (int*)alloc((HPAD + 1) * sizeof(int));
    unsigned* epk2 = (unsigned*)alloc((size_t)N_EDGES * sizeof(unsigned));    // 3.2MB
    unsigned* efin = (unsigned*)alloc((size_t)N_EDGES * sizeof(unsigned));    // 3.2MB
    int* grpoff    = (int*)alloc((size_t)NCHUNKS * 66 * sizeof(int));         // 206KB
    int* cnt_g     = (int*)alloc(N_GRAPHS * sizeof(int));
    int* g_ptr     = (int*)alloc(N_GRAPHS * sizeof(int));
    int* done_flags= (int*)alloc(2 * sizeof(int));
    __hip_bfloat16* hb0 = (__hip_bfloat16*)alloc((size_t)N_NODES * DIM * sizeof(__hip_bfloat16));
    __hip_bfloat16* hb1 = (__hip_bfloat16*)alloc((size_t)N_NODES * DIM * sizeof(__hip_bfloat16));
    __hip_bfloat16* Wt1 = (__hip_bfloat16*)alloc((size_t)N_RELS * DIM * DIM * sizeof(__hip_bfloat16));
    __hip_bfloat16* Wt2 = (__hip_bfloat16*)alloc((size_t)N_RELS * DIM * DIM * sizeof(__hip_bfloat16));
    __hip_bfloat16* Wt3 = (__hip_bfloat16*)alloc((size_t)N_RELS * DIM * DIM * sizeof(__hip_bfloat16));

    // ---- prep + sort (4 dispatches) ----
    prep_kernel<<<SORT_BLOCKS, 256, 0, stream>>>(node_feats, dst, hb0, blk_hist1,
                                                 W1, W2, W3, Wt1, Wt2, Wt3, done_flags);
    chunkscan_kernel<<<NCHUNKS, 256, 0, stream>>>(blk_hist1, blk_off1, chunk_tot,
                                                  chunk_ptr, graph_ids, g_ptr, cnt_g,
                                                  &done_flags[0]);
    scatterc_kernel<<<SORT_BLOCKS, 256, 0, stream>>>(etypes, src, dst, blk_hist1,
                                                     blk_off1, chunk_ptr, epk2);
    chunksort_kernel<<<NCHUNKS, 256, 0, stream>>>(epk2, chunk_ptr, efin, grpoff);

    // ---- 3 fused RGCN layers (messages never hit memory) ----
    layer_kernel<<<NCHUNKS, 256, 0, stream>>>(hb0, Wt1, efin, grpoff, b1, hb1);
    layer_kernel<<<NCHUNKS, 256, 0, stream>>>(hb1, Wt2, efin, grpoff, b2, hb0);
    layer_kernel<<<NCHUNKS, 256, 0, stream>>>(hb0, Wt3, efin, grpoff, b3, hb1);

    // ---- fused pool + FC head ----
    poolfc_kernel<<<(N_GRAPHS + 3) / 4, 256, 0, stream>>>(hb1, g_ptr, cnt_g,
                                                          fcW1, fcb1, fcW2, fcb2,
                                                          fcW3, fcb3, pW, pb, out);
}

// Round 8
// 391.641 us; speedup vs baseline: 3.1724x; 1.3119x over previous
//
#include <hip/hip_runtime.h>
#include <hip/hip_bf16.h>

#define N_NODES 50000
#define N_EDGES 800000
#define N_RELS 65
#define DIM 64
#define N_GRAPHS 512

#define SORT_BLOCKS 1024
#define CHUNK ((N_EDGES + SORT_BLOCKS - 1) / SORT_BLOCKS)  // 782

#define SCAN_BLK 512
#define NSCAN_BLKS ((N_NODES + SCAN_BLK - 1) / SCAN_BLK)   // 98

#define MSG_BLOCKS 2048
#define NWAVES (MSG_BLOCKS * 4)

typedef __attribute__((ext_vector_type(8))) short short8;
typedef __attribute__((ext_vector_type(4))) float f32x4;

// ================= prep (fused): h-convert + zero counters + rel-hist + W transpose =================

__global__ __launch_bounds__(256) void prep_kernel(
    const float* __restrict__ x, const int* __restrict__ et,
    __hip_bfloat16* __restrict__ y, int* __restrict__ cnt_d,
    int* __restrict__ blk_hist,
    const float* __restrict__ W1, const float* __restrict__ W2,
    const float* __restrict__ W3,
    __hip_bfloat16* __restrict__ Wt1, __hip_bfloat16* __restrict__ Wt2,
    __hip_bfloat16* __restrict__ Wt3,
    int* __restrict__ done_flags) {
    __shared__ int lh[N_RELS];
    __shared__ float tile[64][65];
    int t = threadIdx.x, b = blockIdx.x;
    int gtid = b * 256 + t;

    // zero counters (consumed by later kernels only)
    if (gtid < N_NODES) cnt_d[gtid] = 0;
    if (gtid < 2) done_flags[gtid] = 0;

    // per-block relation histogram of this block's edge chunk
    if (t < N_RELS) lh[t] = 0;
    __syncthreads();
    int lo = b * CHUNK;
    int hi = lo + CHUNK; if (hi > N_EDGES) hi = N_EDGES;
    for (int i = lo + t; i < hi; i += 256)
        atomicAdd(&lh[et[i]], 1);

    // grid-stride h conversion (f32 -> bf16, vectorized)
    for (int i = gtid; i < (N_NODES * DIM) / 4; i += SORT_BLOCKS * 256) {
        float4 v = *(const float4*)(x + (size_t)i * 4);
        unsigned short us[4];
        us[0] = __hip_bfloat16_raw(__float2bfloat16(v.x)).x;
        us[1] = __hip_bfloat16_raw(__float2bfloat16(v.y)).x;
        us[2] = __hip_bfloat16_raw(__float2bfloat16(v.z)).x;
        us[3] = __hip_bfloat16_raw(__float2bfloat16(v.w)).x;
        *(ushort4*)(y + (size_t)i * 4) = *(const ushort4*)us;
    }

    // W transpose+convert: blocks 0..194 do one rel tile each (LDS-tiled, coalesced)
    if (b < 3 * N_RELS) {
        int which = b / N_RELS, r = b - which * N_RELS;
        const float* W = (which == 0) ? W1 : (which == 1) ? W2 : W3;
        __hip_bfloat16* Wt = (which == 0) ? Wt1 : (which == 1) ? Wt2 : Wt3;
        for (int i = t; i < 4096; i += 256) {
            int row = i >> 6, col = i & 63;
            tile[row][col] = W[(size_t)r * 4096 + i];
        }
        __syncthreads();
        for (int i = t; i < 4096; i += 256) {
            int row = i >> 6, col = i & 63;
            Wt[(size_t)r * 4096 + i] = __float2bfloat16(tile[col][row]);
        }
    }

    __syncthreads();
    if (t < N_RELS) blk_hist[t * SORT_BLOCKS + b] = lh[t];
}

// ================= relscan: per-relation block-offset scan; last block does reltop =================

__global__ __launch_bounds__(256) void relscan_kernel(const int* __restrict__ blk_hist,
                                                      int* __restrict__ blk_off,
                                                      int* __restrict__ rel_tot,
                                                      int* __restrict__ rel_ptr,
                                                      int* __restrict__ tile_base,
                                                      int* __restrict__ done) {
    __shared__ int wsum[4];
    int r = blockIdx.x;
    int t = threadIdx.x;
    int w = t >> 6, lane = t & 63;
    const int PER = SORT_BLOCKS / 256;  // 4
    int4 v0 = *(const int4*)(blk_hist + (size_t)r * SORT_BLOCKS + t * PER);
    int vals[4] = {v0.x, v0.y, v0.z, v0.w};
    int s = 0;
    #pragma unroll
    for (int j = 0; j < PER; ++j) s += vals[j];
    int x = s;
    #pragma unroll
    for (int off = 1; off < 64; off <<= 1) {
        int y = __shfl_up(x, off);
        if (lane >= off) x += y;
    }
    if (lane == 63) wsum[w] = x;
    __syncthreads();
    int base = 0;
    for (int i = 0; i < w; ++i) base += wsum[i];
    int run = base + x - s;
    int out[4];
    #pragma unroll
    for (int j = 0; j < PER; ++j) { out[j] = run; run += vals[j]; }
    *(int4*)(blk_off + (size_t)r * SORT_BLOCKS + t * PER) = *(const int4*)&out[0];

    if (t == 255) {
        __hip_atomic_store(&rel_tot[r], base + x, __ATOMIC_RELAXED, __HIP_MEMORY_SCOPE_AGENT);
        __threadfence();
        int ticket = atomicAdd(done, 1);
        if (ticket == N_RELS - 1) {          // last block: serial cross-relation scan
            int ss = 0, tt = 0;
            for (int q = 0; q < N_RELS; ++q) {
                int v = __hip_atomic_load(&rel_tot[q], __ATOMIC_RELAXED,
                                          __HIP_MEMORY_SCOPE_AGENT);
                rel_ptr[q] = ss; ss += v;
                tile_base[q] = tt; tt += (v + 15) >> 4;
            }
            rel_ptr[N_RELS] = N_EDGES;
            tile_base[N_RELS] = tt;
        }
    }
}

// ================= scatter: LDS-staged counting sort + fused rank atomic =================

__global__ __launch_bounds__(256) void scatter2_kernel(
    const int* __restrict__ et, const int* __restrict__ src,
    const int* __restrict__ dst, const int* __restrict__ blk_hist,
    const int* __restrict__ blk_off, const int* __restrict__ rel_ptr,
    unsigned long long* __restrict__ epk, int* __restrict__ cnt_d) {
    __shared__ unsigned long long buf[CHUNK];
    __shared__ unsigned char relof[CHUNK];
    __shared__ int loff[N_RELS + 1];
    __shared__ int lcur[N_RELS];
    __shared__ int gbase[N_RELS];
    int t = threadIdx.x, b = blockIdx.x;

    if (t < 64) {
        int v = blk_hist[t * SORT_BLOCKS + b];
        int x = v;
        #pragma unroll
        for (int off = 1; off < 64; off <<= 1) {
            int y = __shfl_up(x, off);
            if (t >= off) x += y;
        }
        loff[t] = x - v;
        lcur[t] = x - v;
        gbase[t] = rel_ptr[t] + blk_off[t * SORT_BLOCKS + b];
        if (t == 63) { loff[64] = x; lcur[64] = x; }
    } else if (t == 64) {
        gbase[64] = rel_ptr[64] + blk_off[64 * SORT_BLOCKS + b];
    }
    __syncthreads();

    int lo = b * CHUNK;
    int hi = lo + CHUNK; if (hi > N_EDGES) hi = N_EDGES;
    int nloc = hi - lo;

    #pragma unroll
    for (int k = 0; k < 4; ++k) {
        int i = lo + t + k * 256;
        if (i < hi) {
            int r = et[i], d = dst[i];
            unsigned s = (unsigned)src[i];
            int rank = atomicAdd(&cnt_d[d], 1);      // degree AND rank in one atomic
            int pl = atomicAdd(&lcur[r], 1);
            unsigned lo32 = s | ((unsigned)d << 16);
            buf[pl] = (unsigned long long)lo32 |
                      ((unsigned long long)(unsigned)rank << 32);
            relof[pl] = (unsigned char)r;
        }
    }
    __syncthreads();

    #pragma unroll
    for (int k = 0; k < 4; ++k) {
        int i = t + k * 256;
        if (i < nloc) {
            int r = relof[i];
            epk[gbase[r] + i - loff[r]] = buf[i];
        }
    }
}

// ================= scanblk: dst CSR partial scan; last block does top scan + g_ptr =================

__global__ __launch_bounds__(SCAN_BLK) void scanblk_kernel(
    const int* __restrict__ cnt, int* __restrict__ outv,
    int* __restrict__ blk_tot, int* __restrict__ blk_base,
    const int* __restrict__ gid, int* __restrict__ g_ptr,
    int* __restrict__ cnt_g, int* __restrict__ done) {
    __shared__ int tmp[SCAN_BLK];
    __shared__ int is_last;
    int t = threadIdx.x;
    int i = blockIdx.x * SCAN_BLK + t;
    int v = (i < N_NODES) ? cnt[i] : 0;
    tmp[t] = v;
    __syncthreads();
    for (int off = 1; off < SCAN_BLK; off <<= 1) {
        int add = (t >= off) ? tmp[t - off] : 0;
        __syncthreads();
        tmp[t] += add;
        __syncthreads();
    }
    if (i < N_NODES) outv[i] = tmp[t] - v;  // block-local exclusive
    if (t == SCAN_BLK - 1) {
        __hip_atomic_store(&blk_tot[blockIdx.x], tmp[t], __ATOMIC_RELAXED,
                           __HIP_MEMORY_SCOPE_AGENT);
        __threadfence();
        int ticket = atomicAdd(done, 1);
        is_last = (ticket == NSCAN_BLKS - 1) ? 1 : 0;
    }
    __syncthreads();
    if (is_last) {
        if (t == 0) {
            int run = 0;
            for (int b2 = 0; b2 < NSCAN_BLKS; ++b2) {
                int v2 = __hip_atomic_load(&blk_tot[b2], __ATOMIC_RELAXED,
                                           __HIP_MEMORY_SCOPE_AGENT);
                blk_base[b2] = run; run += v2;
            }
        }
        // graph segments via binary search (graph_ids is sorted)
        if (t < N_GRAPHS) {
            int g = t;
            int lo2 = 0, hi2 = N_NODES;
            while (lo2 < hi2) { int m = (lo2 + hi2) >> 1; if (gid[m] < g) lo2 = m + 1; else hi2 = m; }
            int a2 = lo2;
            lo2 = 0; hi2 = N_NODES;
            int g1 = g + 1;
            while (lo2 < hi2) { int m = (lo2 + hi2) >> 1; if (gid[m] < g1) lo2 = m + 1; else hi2 = m; }
            g_ptr[g] = a2;
            cnt_g[g] = lo2 - a2;
        }
    }
}

// ================= phase 1: MFMA message kernel — zero-LDS, 4-col-interleaved B,
//                   unpack folded into loadidx (epk -> src, dpos on the fly) =================

__device__ inline unsigned pack2bf(float x, float y) {
    unsigned short ux = __hip_bfloat16_raw(__float2bfloat16(x)).x;
    unsigned short uy = __hip_bfloat16_raw(__float2bfloat16(y)).x;
    return (unsigned)ux | ((unsigned)uy << 16);
}

__global__ __launch_bounds__(256) void msg_mfma_kernel(
    const __hip_bfloat16* __restrict__ hb, const __hip_bfloat16* __restrict__ Wt,
    const int* __restrict__ rel_ptr, const int* __restrict__ tile_base,
    const unsigned long long* __restrict__ epk, const int* __restrict__ outv,
    const int* __restrict__ blk_base,
    __hip_bfloat16* __restrict__ msg) {
    int t = threadIdx.x;
    int w = t >> 6, lane = t & 63;
    int quad = lane >> 4, m16 = lane & 15;
    int wave = blockIdx.x * 4 + w;

    int ntiles = tile_base[N_RELS];
    int tpw = (ntiles + NWAVES - 1) / NWAVES;
    int T = wave * tpw;
    int T1 = T + tpw; if (T1 > ntiles) T1 = ntiles;
    if (T >= T1) return;

    int r = 0;
    while (T >= tile_base[r + 1]) ++r;

    while (T < T1) {
        int chunk_end = tile_base[r + 1]; if (chunk_end > T1) chunk_end = T1;
        int e_base = rel_ptr[r], t_base = tile_base[r];
        int seg_end = rel_ptr[r + 1];

        const __hip_bfloat16* Wr = Wt + (size_t)r * (DIM * DIM);
        short8 bf00 = *(const short8*)(Wr + (4 * m16)     * DIM + quad * 8);
        short8 bf01 = *(const short8*)(Wr + (4 * m16 + 1) * DIM + quad * 8);
        short8 bf02 = *(const short8*)(Wr + (4 * m16 + 2) * DIM + quad * 8);
        short8 bf03 = *(const short8*)(Wr + (4 * m16 + 3) * DIM + quad * 8);
        short8 bf10 = *(const short8*)(Wr + (4 * m16)     * DIM + 32 + quad * 8);
        short8 bf11 = *(const short8*)(Wr + (4 * m16 + 1) * DIM + 32 + quad * 8);
        short8 bf12 = *(const short8*)(Wr + (4 * m16 + 2) * DIM + 32 + quad * 8);
        short8 bf13 = *(const short8*)(Wr + (4 * m16 + 3) * DIM + 32 + quad * 8);

        // loadidx: epk record -> (src, dpos). outv/blk_base are small (L2-hot);
        // the dependent load chain sits 2 tile-iterations ahead of use.
        auto loadidx = [&](int TT, int& sv, int& dp) {
            int TC = TT < chunk_end ? TT : chunk_end - 1;
            int i = e_base + (TC - t_base) * 16 + lane;
            if (i >= N_EDGES) i = N_EDGES - 1;
            unsigned long long e = epk[i];
            int d = (int)((e >> 16) & 0xFFFFu);
            sv = (int)(e & 0xFFFFu);
            dp = (int)(e >> 32) + outv[d] + blk_base[d >> 9];
        };
        auto gatherA = [&](int sv, short8& x0, short8& x1) {
            int s = __shfl(sv, m16);
            const __hip_bfloat16* hp = hb + (size_t)s * DIM + quad * 8;
            x0 = *(const short8*)hp;
            x1 = *(const short8*)(hp + 32);
        };

        int sv0, dp0, sv1, dp1, sv2, dp2;
        short8 a0c, a1c, a0n, a1n;
        loadidx(T,     sv0, dp0);
        loadidx(T + 1, sv1, dp1);
        gatherA(sv0, a0c, a1c);

        for (; T < chunk_end; ++T) {
            loadidx(T + 2, sv2, dp2);
            gatherA(sv1, a0n, a1n);

            int e0 = e_base + (T - t_base) * 16;
            int rows = seg_end - e0; if (rows > 16) rows = 16;

            f32x4 c0 = {0.f, 0.f, 0.f, 0.f}, c1 = c0, c2 = c0, c3 = c0;
            c0 = __builtin_amdgcn_mfma_f32_16x16x32_bf16(a0c, bf00, c0, 0, 0, 0);
            c1 = __builtin_amdgcn_mfma_f32_16x16x32_bf16(a0c, bf01, c1, 0, 0, 0);
            c2 = __builtin_amdgcn_mfma_f32_16x16x32_bf16(a0c, bf02, c2, 0, 0, 0);
            c3 = __builtin_amdgcn_mfma_f32_16x16x32_bf16(a0c, bf03, c3, 0, 0, 0);
            c0 = __builtin_amdgcn_mfma_f32_16x16x32_bf16(a1c, bf10, c0, 0, 0, 0);
            c1 = __builtin_amdgcn_mfma_f32_16x16x32_bf16(a1c, bf11, c1, 0, 0, 0);
            c2 = __builtin_amdgcn_mfma_f32_16x16x32_bf16(a1c, bf12, c2, 0, 0, 0);
            c3 = __builtin_amdgcn_mfma_f32_16x16x32_bf16(a1c, bf13, c3, 0, 0, 0);

            int dpr[4];
            #pragma unroll
            for (int g = 0; g < 4; ++g) dpr[g] = __shfl(dp0, quad * 4 + g);

            #pragma unroll
            for (int g = 0; g < 4; ++g) {
                if (quad * 4 + g < rows) {
                    uint2 pk;
                    pk.x = pack2bf(c0[g], c1[g]);
                    pk.y = pack2bf(c2[g], c3[g]);
                    *(uint2*)(msg + (size_t)dpr[g] * DIM + 4 * m16) = pk;
                }
            }

            sv0 = sv1; dp0 = dp1; sv1 = sv2; dp1 = dp2;
            a0c = a0n; a1c = a1n;
        }
        ++r;
        while (T < T1 && T >= tile_base[r + 1]) ++r;
    }
}

// ================= phase 2: vectorized pull-aggregate + bias + ReLU =================

__global__ __launch_bounds__(256) void agg_kernel(
    const __hip_bfloat16* __restrict__ msg, const int* __restrict__ outv,
    const int* __restrict__ blk_base,
    const int* __restrict__ cnt_d, const float* __restrict__ b,
    __hip_bfloat16* __restrict__ hout) {
    int wave = blockIdx.x * 4 + (threadIdx.x >> 6);
    int lane = threadIdx.x & 63;
    if (wave >= N_NODES) return;
    int j0 = outv[wave] + blk_base[wave >> 9];
    int n  = cnt_d[wave];
    int rgrp = lane >> 3, dgrp = lane & 7;

    float a[8] = {0.f, 0.f, 0.f, 0.f, 0.f, 0.f, 0.f, 0.f};
    for (int jj = 0; jj < n; jj += 8) {
        int row = jj + rgrp;
        if (row < n) {
            uint4 d = *(const uint4*)(msg + (size_t)(j0 + row) * DIM + dgrp * 8);
            a[0] += __uint_as_float(d.x << 16);
            a[1] += __uint_as_float(d.x & 0xffff0000u);
            a[2] += __uint_as_float(d.y << 16);
            a[3] += __uint_as_float(d.y & 0xffff0000u);
            a[4] += __uint_as_float(d.z << 16);
            a[5] += __uint_as_float(d.z & 0xffff0000u);
            a[6] += __uint_as_float(d.w << 16);
            a[7] += __uint_as_float(d.w & 0xffff0000u);
        }
    }
    #pragma unroll
    for (int i = 0; i < 8; ++i) {
        a[i] += __shfl_xor(a[i], 8);
        a[i] += __shfl_xor(a[i], 16);
        a[i] += __shfl_xor(a[i], 32);
    }
    if (rgrp == 0) {
        unsigned short us[8];
        #pragma unroll
        for (int i = 0; i < 8; ++i) {
            float v = a[i] + b[dgrp * 8 + i];
            us[i] = __hip_bfloat16_raw(__float2bfloat16(v > 0.f ? v : 0.f)).x;
        }
        *(uint4*)(hout + (size_t)wave * DIM + dgrp * 8) = *(const uint4*)us;
    }
}

// ================= fused pool + FC x3 + prediction head =================

__global__ __launch_bounds__(256) void poolfc_kernel(
    const __hip_bfloat16* __restrict__ h, const int* __restrict__ g_ptr,
    const int* __restrict__ cnt_g,
    const float* __restrict__ W1, const float* __restrict__ b1,
    const float* __restrict__ W2, const float* __restrict__ b2,
    const float* __restrict__ W3, const float* __restrict__ b3,
    const float* __restrict__ pW, const float* __restrict__ pb,
    float* __restrict__ out) {
    int wave = blockIdx.x * 4 + (threadIdx.x >> 6);
    int lane = threadIdx.x & 63;
    if (wave >= N_GRAPHS) return;
    int j0 = g_ptr[wave];
    int n  = cnt_g[wave];
    int rgrp = lane >> 3, dgrp = lane & 7;

    float a[8] = {0.f, 0.f, 0.f, 0.f, 0.f, 0.f, 0.f, 0.f};
    for (int jj = 0; jj < n; jj += 8) {
        int row = jj + rgrp;
        if (row < n) {
            uint4 d = *(const uint4*)(h + (size_t)(j0 + row) * DIM + dgrp * 8);
            a[0] += __uint_as_float(d.x << 16);
            a[1] += __uint_as_float(d.x & 0xffff0000u);
            a[2] += __uint_as_float(d.y << 16);
            a[3] += __uint_as_float(d.y & 0xffff0000u);
            a[4] += __uint_as_float(d.z << 16);
            a[5] += __uint_as_float(d.z & 0xffff0000u);
            a[6] += __uint_as_float(d.w << 16);
            a[7] += __uint_as_float(d.w & 0xffff0000u);
        }
    }
    #pragma unroll
    for (int i = 0; i < 8; ++i) {
        a[i] += __shfl_xor(a[i], 8);
        a[i] += __shfl_xor(a[i], 16);
        a[i] += __shfl_xor(a[i], 32);
    }
    float v;
    {
        float acc = b1[lane];
        #pragma unroll
        for (int o = 0; o < 8; ++o)
            #pragma unroll
            for (int q = 0; q < 8; ++q)
                acc += __shfl(a[o], q) * W1[(q * 8 + o) * DIM + lane];
        v = acc > 0.f ? acc : 0.f;
    }
    {
        float acc = b2[lane];
        #pragma unroll
        for (int d = 0; d < DIM; ++d)
            acc += __shfl(v, d) * W2[d * DIM + lane];
        v = acc > 0.f ? acc : 0.f;
    }
    {
        float acc = b3[lane];
        #pragma unroll
        for (int d = 0; d < DIM; ++d)
            acc += __shfl(v, d) * W3[d * DIM + lane];
        v = acc > 0.f ? acc : 0.f;
    }
    float p0 = v * pW[lane * 2 + 0];
    float p1 = v * pW[lane * 2 + 1];
    #pragma unroll
    for (int off = 32; off > 0; off >>= 1) {
        p0 += __shfl_down(p0, off);
        p1 += __shfl_down(p1, off);
    }
    if (lane == 0) {
        out[wave * 2 + 0] = p0 + pb[0];
        out[wave * 2 + 1] = p1 + pb[1];
    }
}

// ================= launch =================

extern "C" void kernel_launch(void* const* d_in, const int* in_sizes, int n_in,
                              void* d_out, int out_size, void* d_ws, size_t ws_size,
                              hipStream_t stream) {
    const float* node_feats = (const float*)d_in[0];
    const int*   etypes     = (const int*)d_in[1];
    const int*   src        = (const int*)d_in[2];
    const int*   dst        = (const int*)d_in[3];
    const int*   graph_ids  = (const int*)d_in[4];
    const float* W1 = (const float*)d_in[5];
    const float* b1 = (const float*)d_in[6];
    const float* W2 = (const float*)d_in[7];
    const float* b2 = (const float*)d_in[8];
    const float* W3 = (const float*)d_in[9];
    const float* b3 = (const float*)d_in[10];
    const float* fcW1 = (const float*)d_in[11];
    const float* fcb1 = (const float*)d_in[12];
    const float* fcW2 = (const float*)d_in[13];
    const float* fcb2 = (const float*)d_in[14];
    const float* fcW3 = (const float*)d_in[15];
    const float* fcb3 = (const float*)d_in[16];
    const float* pW = (const float*)d_in[17];
    const float* pb = (const float*)d_in[18];
    float* out = (float*)d_out;

    // workspace carve-up (256B aligned)
    char* p = (char*)d_ws;
    auto alloc = [&](size_t bytes) -> void* {
        void* r = (void*)p;
        p += (bytes + 255) & ~(size_t)255;
        return r;
    };
    int* blk_hist  = (int*)alloc((size_t)SORT_BLOCKS * N_RELS * sizeof(int));
    int* blk_off   = (int*)alloc((size_t)SORT_BLOCKS * N_RELS * sizeof(int));
    int* rel_ptr   = (int*)alloc((N_RELS + 1) * sizeof(int));
    int* rel_tot   = (int*)alloc(N_RELS * sizeof(int));
    int* tile_base = (int*)alloc((N_RELS + 1) * sizeof(int));
    unsigned long long* epk = (unsigned long long*)alloc((size_t)N_EDGES * sizeof(unsigned long long));
    int* cnt_d     = (int*)alloc((size_t)N_NODES * sizeof(int));
    int* outv      = (int*)alloc((size_t)N_NODES * sizeof(int));
    int* blk_tot   = (int*)alloc(NSCAN_BLKS * sizeof(int));
    int* blk_base  = (int*)alloc(NSCAN_BLKS * sizeof(int));
    int* cnt_g     = (int*)alloc(N_GRAPHS * sizeof(int));
    int* g_ptr     = (int*)alloc(N_GRAPHS * sizeof(int));
    int* done_flags= (int*)alloc(2 * sizeof(int));
    __hip_bfloat16* hb0 = (__hip_bfloat16*)alloc((size_t)N_NODES * DIM * sizeof(__hip_bfloat16));
    __hip_bfloat16* hb1 = (__hip_bfloat16*)alloc((size_t)N_NODES * DIM * sizeof(__hip_bfloat16));
    __hip_bfloat16* Wt1 = (__hip_bfloat16*)alloc((size_t)N_RELS * DIM * DIM * sizeof(__hip_bfloat16));
    __hip_bfloat16* Wt2 = (__hip_bfloat16*)alloc((size_t)N_RELS * DIM * DIM * sizeof(__hip_bfloat16));
    __hip_bfloat16* Wt3 = (__hip_bfloat16*)alloc((size_t)N_RELS * DIM * DIM * sizeof(__hip_bfloat16));
    __hip_bfloat16* msg = (__hip_bfloat16*)alloc((size_t)N_EDGES * DIM * sizeof(__hip_bfloat16));

    const int AGG_BLOCKS = (N_NODES + 3) / 4;            // 12500

    // ---- prep (4 dispatches before layers) ----
    prep_kernel<<<SORT_BLOCKS, 256, 0, stream>>>(node_feats, etypes, hb0, cnt_d, blk_hist,
                                                 W1, W2, W3, Wt1, Wt2, Wt3, done_flags);
    relscan_kernel<<<N_RELS, 256, 0, stream>>>(blk_hist, blk_off, rel_tot,
                                               rel_ptr, tile_base, &done_flags[0]);
    scatter2_kernel<<<SORT_BLOCKS, 256, 0, stream>>>(etypes, src, dst, blk_hist, blk_off,
                                                     rel_ptr, epk, cnt_d);
    scanblk_kernel<<<NSCAN_BLKS, SCAN_BLK, 0, stream>>>(cnt_d, outv, blk_tot, blk_base,
                                                        graph_ids, g_ptr, cnt_g,
                                                        &done_flags[1]);

    // ---- 3 RGCN layers ----
    msg_mfma_kernel<<<MSG_BLOCKS, 256, 0, stream>>>(hb0, Wt1, rel_ptr, tile_base,
                                                    epk, outv, blk_base, msg);
    agg_kernel<<<AGG_BLOCKS, 256, 0, stream>>>(msg, outv, blk_base, cnt_d, b1, hb1);

    msg_mfma_kernel<<<MSG_BLOCKS, 256, 0, stream>>>(hb1, Wt2, rel_ptr, tile_base,
                                                    epk, outv, blk_base, msg);
    agg_kernel<<<AGG_BLOCKS, 256, 0, stream>>>(msg, outv, blk_base, cnt_d, b2, hb0);

    msg_mfma_kernel<<<MSG_BLOCKS, 256, 0, stream>>>(hb0, Wt3, rel_ptr, tile_base,
                                                    epk, outv, blk_base, msg);
    agg_kernel<<<AGG_BLOCKS, 256, 0, stream>>>(msg, outv, blk_base, cnt_d, b3, hb1);

    // ---- fused pool + FC head ----
    poolfc_kernel<<<(N_GRAPHS + 3) / 4, 256, 0, stream>>>(hb1, g_ptr, cnt_g,
                                                          fcW1, fcb1, fcW2, fcb2,
                                                          fcW3, fcb3, pW, pb, out);
}

// Round 9
// 379.597 us; speedup vs baseline: 3.2731x; 1.0317x over previous
//
#include <hip/hip_runtime.h>
#include <hip/hip_bf16.h>

#define N_NODES 50000
#define N_EDGES 800000
#define N_RELS 65
#define DIM 64
#define N_GRAPHS 512

#define SORT_BLOCKS 1024
#define CHUNK ((N_EDGES + SORT_BLOCKS - 1) / SORT_BLOCKS)  // 782

#define SCAN_BLK 512
#define NSCAN_BLKS ((N_NODES + SCAN_BLK - 1) / SCAN_BLK)   // 98

#define MSG_BLOCKS 2048
#define NWAVES (MSG_BLOCKS * 4)

typedef __attribute__((ext_vector_type(8))) short short8;
typedef __attribute__((ext_vector_type(4))) float f32x4;
typedef __attribute__((ext_vector_type(2))) unsigned u32x2;
typedef __attribute__((ext_vector_type(4))) unsigned u32x4;

// ================= prep (fused): h-convert + zero counters + rel-hist + W transpose =================

__global__ __launch_bounds__(256) void prep_kernel(
    const float* __restrict__ x, const int* __restrict__ et,
    __hip_bfloat16* __restrict__ y, int* __restrict__ cnt_d,
    int* __restrict__ blk_hist,
    const float* __restrict__ W1, const float* __restrict__ W2,
    const float* __restrict__ W3,
    __hip_bfloat16* __restrict__ Wt1, __hip_bfloat16* __restrict__ Wt2,
    __hip_bfloat16* __restrict__ Wt3,
    int* __restrict__ done_flags) {
    __shared__ int lh[N_RELS];
    __shared__ float tile[64][65];
    int t = threadIdx.x, b = blockIdx.x;
    int gtid = b * 256 + t;

    if (gtid < N_NODES) cnt_d[gtid] = 0;
    if (gtid < 2) done_flags[gtid] = 0;

    if (t < N_RELS) lh[t] = 0;
    __syncthreads();
    int lo = b * CHUNK;
    int hi = lo + CHUNK; if (hi > N_EDGES) hi = N_EDGES;
    for (int i = lo + t; i < hi; i += 256)
        atomicAdd(&lh[et[i]], 1);

    for (int i = gtid; i < (N_NODES * DIM) / 4; i += SORT_BLOCKS * 256) {
        float4 v = *(const float4*)(x + (size_t)i * 4);
        unsigned short us[4];
        us[0] = __hip_bfloat16_raw(__float2bfloat16(v.x)).x;
        us[1] = __hip_bfloat16_raw(__float2bfloat16(v.y)).x;
        us[2] = __hip_bfloat16_raw(__float2bfloat16(v.z)).x;
        us[3] = __hip_bfloat16_raw(__float2bfloat16(v.w)).x;
        *(ushort4*)(y + (size_t)i * 4) = *(const ushort4*)us;
    }

    if (b < 3 * N_RELS) {
        int which = b / N_RELS, r = b - which * N_RELS;
        const float* W = (which == 0) ? W1 : (which == 1) ? W2 : W3;
        __hip_bfloat16* Wt = (which == 0) ? Wt1 : (which == 1) ? Wt2 : Wt3;
        for (int i = t; i < 4096; i += 256) {
            int row = i >> 6, col = i & 63;
            tile[row][col] = W[(size_t)r * 4096 + i];
        }
        __syncthreads();
        for (int i = t; i < 4096; i += 256) {
            int row = i >> 6, col = i & 63;
            Wt[(size_t)r * 4096 + i] = __float2bfloat16(tile[col][row]);
        }
    }

    __syncthreads();
    if (t < N_RELS) blk_hist[t * SORT_BLOCKS + b] = lh[t];
}

// ================= relscan: per-relation block-offset scan; last block does reltop =================

__global__ __launch_bounds__(256) void relscan_kernel(const int* __restrict__ blk_hist,
                                                      int* __restrict__ blk_off,
                                                      int* __restrict__ rel_tot,
                                                      int* __restrict__ rel_ptr,
                                                      int* __restrict__ tile_base,
                                                      int* __restrict__ done) {
    __shared__ int wsum[4];
    int r = blockIdx.x;
    int t = threadIdx.x;
    int w = t >> 6, lane = t & 63;
    const int PER = SORT_BLOCKS / 256;  // 4
    int4 v0 = *(const int4*)(blk_hist + (size_t)r * SORT_BLOCKS + t * PER);
    int vals[4] = {v0.x, v0.y, v0.z, v0.w};
    int s = 0;
    #pragma unroll
    for (int j = 0; j < PER; ++j) s += vals[j];
    int x = s;
    #pragma unroll
    for (int off = 1; off < 64; off <<= 1) {
        int y = __shfl_up(x, off);
        if (lane >= off) x += y;
    }
    if (lane == 63) wsum[w] = x;
    __syncthreads();
    int base = 0;
    for (int i = 0; i < w; ++i) base += wsum[i];
    int run = base + x - s;
    int out[4];
    #pragma unroll
    for (int j = 0; j < PER; ++j) { out[j] = run; run += vals[j]; }
    *(int4*)(blk_off + (size_t)r * SORT_BLOCKS + t * PER) = *(const int4*)&out[0];

    if (t == 255) {
        __hip_atomic_store(&rel_tot[r], base + x, __ATOMIC_RELAXED, __HIP_MEMORY_SCOPE_AGENT);
        __threadfence();
        int ticket = atomicAdd(done, 1);
        if (ticket == N_RELS - 1) {          // last block: serial cross-relation scan
            int ss = 0, tt = 0;
            for (int q = 0; q < N_RELS; ++q) {
                int v = __hip_atomic_load(&rel_tot[q], __ATOMIC_RELAXED,
                                          __HIP_MEMORY_SCOPE_AGENT);
                rel_ptr[q] = ss; ss += v;
                tile_base[q] = tt; tt += (v + 15) >> 4;
            }
            rel_ptr[N_RELS] = N_EDGES;
            tile_base[N_RELS] = tt;
        }
    }
}

// ================= scatter: LDS-staged counting sort + fused rank atomic =================

__global__ __launch_bounds__(256) void scatter2_kernel(
    const int* __restrict__ et, const int* __restrict__ src,
    const int* __restrict__ dst, const int* __restrict__ blk_hist,
    const int* __restrict__ blk_off, const int* __restrict__ rel_ptr,
    unsigned long long* __restrict__ epk, int* __restrict__ cnt_d) {
    __shared__ unsigned long long buf[CHUNK];
    __shared__ unsigned char relof[CHUNK];
    __shared__ int loff[N_RELS + 1];
    __shared__ int lcur[N_RELS];
    __shared__ int gbase[N_RELS];
    int t = threadIdx.x, b = blockIdx.x;

    if (t < 64) {
        int v = blk_hist[t * SORT_BLOCKS + b];
        int x = v;
        #pragma unroll
        for (int off = 1; off < 64; off <<= 1) {
            int y = __shfl_up(x, off);
            if (t >= off) x += y;
        }
        loff[t] = x - v;
        lcur[t] = x - v;
        gbase[t] = rel_ptr[t] + blk_off[t * SORT_BLOCKS + b];
        if (t == 63) { loff[64] = x; lcur[64] = x; }
    } else if (t == 64) {
        gbase[64] = rel_ptr[64] + blk_off[64 * SORT_BLOCKS + b];
    }
    __syncthreads();

    int lo = b * CHUNK;
    int hi = lo + CHUNK; if (hi > N_EDGES) hi = N_EDGES;
    int nloc = hi - lo;

    #pragma unroll
    for (int k = 0; k < 4; ++k) {
        int i = lo + t + k * 256;
        if (i < hi) {
            int r = et[i], d = dst[i];
            unsigned s = (unsigned)src[i];
            int rank = atomicAdd(&cnt_d[d], 1);      // degree AND rank in one atomic
            int pl = atomicAdd(&lcur[r], 1);
            unsigned lo32 = s | ((unsigned)d << 16);
            buf[pl] = (unsigned long long)lo32 |
                      ((unsigned long long)(unsigned)rank << 32);
            relof[pl] = (unsigned char)r;
        }
    }
    __syncthreads();

    #pragma unroll
    for (int k = 0; k < 4; ++k) {
        int i = t + k * 256;
        if (i < nloc) {
            int r = relof[i];
            epk[gbase[r] + i - loff[r]] = buf[i];
        }
    }
}

// ================= scanblk: dst CSR partial scan; last block does top scan + g_ptr =================

__global__ __launch_bounds__(SCAN_BLK) void scanblk_kernel(
    const int* __restrict__ cnt, int* __restrict__ outv,
    int* __restrict__ blk_tot, int* __restrict__ blk_base,
    const int* __restrict__ gid, int* __restrict__ g_ptr,
    int* __restrict__ cnt_g, int* __restrict__ done) {
    __shared__ int tmp[SCAN_BLK];
    __shared__ int is_last;
    int t = threadIdx.x;
    int i = blockIdx.x * SCAN_BLK + t;
    int v = (i < N_NODES) ? cnt[i] : 0;
    tmp[t] = v;
    __syncthreads();
    for (int off = 1; off < SCAN_BLK; off <<= 1) {
        int add = (t >= off) ? tmp[t - off] : 0;
        __syncthreads();
        tmp[t] += add;
        __syncthreads();
    }
    if (i < N_NODES) outv[i] = tmp[t] - v;  // block-local exclusive
    if (t == SCAN_BLK - 1) {
        __hip_atomic_store(&blk_tot[blockIdx.x], tmp[t], __ATOMIC_RELAXED,
                           __HIP_MEMORY_SCOPE_AGENT);
        __threadfence();
        int ticket = atomicAdd(done, 1);
        is_last = (ticket == NSCAN_BLKS - 1) ? 1 : 0;
    }
    __syncthreads();
    if (is_last) {
        if (t == 0) {
            int run = 0;
            for (int b2 = 0; b2 < NSCAN_BLKS; ++b2) {
                int v2 = __hip_atomic_load(&blk_tot[b2], __ATOMIC_RELAXED,
                                           __HIP_MEMORY_SCOPE_AGENT);
                blk_base[b2] = run; run += v2;
            }
        }
        // graph segments via binary search (graph_ids is sorted)
        if (t < N_GRAPHS) {
            int g = t;
            int lo2 = 0, hi2 = N_NODES;
            while (lo2 < hi2) { int m = (lo2 + hi2) >> 1; if (gid[m] < g) lo2 = m + 1; else hi2 = m; }
            int a2 = lo2;
            lo2 = 0; hi2 = N_NODES;
            int g1 = g + 1;
            while (lo2 < hi2) { int m = (lo2 + hi2) >> 1; if (gid[m] < g1) lo2 = m + 1; else hi2 = m; }
            g_ptr[g] = a2;
            cnt_g[g] = lo2 - a2;
        }
    }
}

// ================= unpack: dependent index math done ONCE, streaming (R8 lesson) =================

__global__ void unpack_kernel(const unsigned long long* __restrict__ epk,
                              const int* __restrict__ outv,
                              const int* __restrict__ blk_base,
                              int* __restrict__ src_s, int* __restrict__ dpos) {
    int i = blockIdx.x * 256 + threadIdx.x;
    if (i < N_EDGES) {
        unsigned long long e = epk[i];
        int s = (int)(e & 0xFFFFu);
        int d = (int)((e >> 16) & 0xFFFFu);
        int rank = (int)(e >> 32);
        src_s[i] = s;
        dpos[i] = rank + outv[d] + blk_base[d >> 9];
    }
}

// ================= phase 1: MFMA message kernel — zero-LDS, 4-col-interleaved B,
//                   NON-TEMPORAL msg stores (msg stream must not evict hb from L2) =================

__device__ inline unsigned pack2bf(float x, float y) {
    unsigned short ux = __hip_bfloat16_raw(__float2bfloat16(x)).x;
    unsigned short uy = __hip_bfloat16_raw(__float2bfloat16(y)).x;
    return (unsigned)ux | ((unsigned)uy << 16);
}

__global__ __launch_bounds__(256) void msg_mfma_kernel(
    const __hip_bfloat16* __restrict__ hb, const __hip_bfloat16* __restrict__ Wt,
    const int* __restrict__ rel_ptr, const int* __restrict__ tile_base,
    const int* __restrict__ src_s, const int* __restrict__ dpos,
    __hip_bfloat16* __restrict__ msg) {
    int t = threadIdx.x;
    int w = t >> 6, lane = t & 63;
    int quad = lane >> 4, m16 = lane & 15;
    int wave = blockIdx.x * 4 + w;

    int ntiles = tile_base[N_RELS];
    int tpw = (ntiles + NWAVES - 1) / NWAVES;
    int T = wave * tpw;
    int T1 = T + tpw; if (T1 > ntiles) T1 = ntiles;
    if (T >= T1) return;

    int r = 0;
    while (T >= tile_base[r + 1]) ++r;

    while (T < T1) {
        int chunk_end = tile_base[r + 1]; if (chunk_end > T1) chunk_end = T1;
        int e_base = rel_ptr[r], t_base = tile_base[r];
        int seg_end = rel_ptr[r + 1];

        const __hip_bfloat16* Wr = Wt + (size_t)r * (DIM * DIM);
        short8 bf00 = *(const short8*)(Wr + (4 * m16)     * DIM + quad * 8);
        short8 bf01 = *(const short8*)(Wr + (4 * m16 + 1) * DIM + quad * 8);
        short8 bf02 = *(const short8*)(Wr + (4 * m16 + 2) * DIM + quad * 8);
        short8 bf03 = *(const short8*)(Wr + (4 * m16 + 3) * DIM + quad * 8);
        short8 bf10 = *(const short8*)(Wr + (4 * m16)     * DIM + 32 + quad * 8);
        short8 bf11 = *(const short8*)(Wr + (4 * m16 + 1) * DIM + 32 + quad * 8);
        short8 bf12 = *(const short8*)(Wr + (4 * m16 + 2) * DIM + 32 + quad * 8);
        short8 bf13 = *(const short8*)(Wr + (4 * m16 + 3) * DIM + 32 + quad * 8);

        auto loadidx = [&](int TT, int& sv, int& dp) {
            int TC = TT < chunk_end ? TT : chunk_end - 1;
            int i = e_base + (TC - t_base) * 16 + lane;
            if (i >= N_EDGES) i = N_EDGES - 1;
            sv = src_s[i]; dp = dpos[i];
        };
        auto gatherA = [&](int sv, short8& x0, short8& x1) {
            int s = __shfl(sv, m16);
            const __hip_bfloat16* hp = hb + (size_t)s * DIM + quad * 8;
            x0 = *(const short8*)hp;
            x1 = *(const short8*)(hp + 32);
        };

        int sv0, dp0, sv1, dp1, sv2, dp2;
        short8 a0c, a1c, a0n, a1n;
        loadidx(T,     sv0, dp0);
        loadidx(T + 1, sv1, dp1);
        gatherA(sv0, a0c, a1c);

        for (; T < chunk_end; ++T) {
            loadidx(T + 2, sv2, dp2);
            gatherA(sv1, a0n, a1n);

            int e0 = e_base + (T - t_base) * 16;
            int rows = seg_end - e0; if (rows > 16) rows = 16;

            f32x4 c0 = {0.f, 0.f, 0.f, 0.f}, c1 = c0, c2 = c0, c3 = c0;
            c0 = __builtin_amdgcn_mfma_f32_16x16x32_bf16(a0c, bf00, c0, 0, 0, 0);
            c1 = __builtin_amdgcn_mfma_f32_16x16x32_bf16(a0c, bf01, c1, 0, 0, 0);
            c2 = __builtin_amdgcn_mfma_f32_16x16x32_bf16(a0c, bf02, c2, 0, 0, 0);
            c3 = __builtin_amdgcn_mfma_f32_16x16x32_bf16(a0c, bf03, c3, 0, 0, 0);
            c0 = __builtin_amdgcn_mfma_f32_16x16x32_bf16(a1c, bf10, c0, 0, 0, 0);
            c1 = __builtin_amdgcn_mfma_f32_16x16x32_bf16(a1c, bf11, c1, 0, 0, 0);
            c2 = __builtin_amdgcn_mfma_f32_16x16x32_bf16(a1c, bf12, c2, 0, 0, 0);
            c3 = __builtin_amdgcn_mfma_f32_16x16x32_bf16(a1c, bf13, c3, 0, 0, 0);

            int dpr[4];
            #pragma unroll
            for (int g = 0; g < 4; ++g) dpr[g] = __shfl(dp0, quad * 4 + g);

            #pragma unroll
            for (int g = 0; g < 4; ++g) {
                if (quad * 4 + g < rows) {
                    u32x2 pk;
                    pk[0] = pack2bf(c0[g], c1[g]);
                    pk[1] = pack2bf(c2[g], c3[g]);
                    __builtin_nontemporal_store(
                        pk, (u32x2*)(msg + (size_t)dpr[g] * DIM + 4 * m16));
                }
            }

            sv0 = sv1; dp0 = dp1; sv1 = sv2; dp1 = dp2;
            a0c = a0n; a1c = a1n;
        }
        ++r;
        while (T < T1 && T >= tile_base[r + 1]) ++r;
    }
}

// ================= phase 2: pull-aggregate, NON-TEMPORAL msg reads (read-once stream) =================

__global__ __launch_bounds__(256) void agg_kernel(
    const __hip_bfloat16* __restrict__ msg, const int* __restrict__ outv,
    const int* __restrict__ blk_base,
    const int* __restrict__ cnt_d, const float* __restrict__ b,
    __hip_bfloat16* __restrict__ hout) {
    int wave = blockIdx.x * 4 + (threadIdx.x >> 6);
    int lane = threadIdx.x & 63;
    if (wave >= N_NODES) return;
    int j0 = outv[wave] + blk_base[wave >> 9];
    int n  = cnt_d[wave];
    int rgrp = lane >> 3, dgrp = lane & 7;

    float a[8] = {0.f, 0.f, 0.f, 0.f, 0.f, 0.f, 0.f, 0.f};
    for (int jj = 0; jj < n; jj += 8) {
        int row = jj + rgrp;
        if (row < n) {
            u32x4 d = __builtin_nontemporal_load(
                (const u32x4*)(msg + (size_t)(j0 + row) * DIM + dgrp * 8));
            a[0] += __uint_as_float(d[0] << 16);
            a[1] += __uint_as_float(d[0] & 0xffff0000u);
            a[2] += __uint_as_float(d[1] << 16);
            a[3] += __uint_as_float(d[1] & 0xffff0000u);
            a[4] += __uint_as_float(d[2] << 16);
            a[5] += __uint_as_float(d[2] & 0xffff0000u);
            a[6] += __uint_as_float(d[3] << 16);
            a[7] += __uint_as_float(d[3] & 0xffff0000u);
        }
    }
    #pragma unroll
    for (int i = 0; i < 8; ++i) {
        a[i] += __shfl_xor(a[i], 8);
        a[i] += __shfl_xor(a[i], 16);
        a[i] += __shfl_xor(a[i], 32);
    }
    if (rgrp == 0) {
        unsigned short us[8];
        #pragma unroll
        for (int i = 0; i < 8; ++i) {
            float v = a[i] + b[dgrp * 8 + i];
            us[i] = __hip_bfloat16_raw(__float2bfloat16(v > 0.f ? v : 0.f)).x;
        }
        *(uint4*)(hout + (size_t)wave * DIM + dgrp * 8) = *(const uint4*)us;
    }
}

// ================= fused pool + FC x3 + prediction head =================

__global__ __launch_bounds__(256) void poolfc_kernel(
    const __hip_bfloat16* __restrict__ h, const int* __restrict__ g_ptr,
    const int* __restrict__ cnt_g,
    const float* __restrict__ W1, const float* __restrict__ b1,
    const float* __restrict__ W2, const float* __restrict__ b2,
    const float* __restrict__ W3, const float* __restrict__ b3,
    const float* __restrict__ pW, const float* __restrict__ pb,
    float* __restrict__ out) {
    int wave = blockIdx.x * 4 + (threadIdx.x >> 6);
    int lane = threadIdx.x & 63;
    if (wave >= N_GRAPHS) return;
    int j0 = g_ptr[wave];
    int n  = cnt_g[wave];
    int rgrp = lane >> 3, dgrp = lane & 7;

    float a[8] = {0.f, 0.f, 0.f, 0.f, 0.f, 0.f, 0.f, 0.f};
    for (int jj = 0; jj < n; jj += 8) {
        int row = jj + rgrp;
        if (row < n) {
            uint4 d = *(const uint4*)(h + (size_t)(j0 + row) * DIM + dgrp * 8);
            a[0] += __uint_as_float(d.x << 16);
            a[1] += __uint_as_float(d.x & 0xffff0000u);
            a[2] += __uint_as_float(d.y << 16);
            a[3] += __uint_as_float(d.y & 0xffff0000u);
            a[4] += __uint_as_float(d.z << 16);
            a[5] += __uint_as_float(d.z & 0xffff0000u);
            a[6] += __uint_as_float(d.w << 16);
            a[7] += __uint_as_float(d.w & 0xffff0000u);
        }
    }
    #pragma unroll
    for (int i = 0; i < 8; ++i) {
        a[i] += __shfl_xor(a[i], 8);
        a[i] += __shfl_xor(a[i], 16);
        a[i] += __shfl_xor(a[i], 32);
    }
    float v;
    {
        float acc = b1[lane];
        #pragma unroll
        for (int o = 0; o < 8; ++o)
            #pragma unroll
            for (int q = 0; q < 8; ++q)
                acc += __shfl(a[o], q) * W1[(q * 8 + o) * DIM + lane];
        v = acc > 0.f ? acc : 0.f;
    }
    {
        float acc = b2[lane];
        #pragma unroll
        for (int d = 0; d < DIM; ++d)
            acc += __shfl(v, d) * W2[d * DIM + lane];
        v = acc > 0.f ? acc : 0.f;
    }
    {
        float acc = b3[lane];
        #pragma unroll
        for (int d = 0; d < DIM; ++d)
            acc += __shfl(v, d) * W3[d * DIM + lane];
        v = acc > 0.f ? acc : 0.f;
    }
    float p0 = v * pW[lane * 2 + 0];
    float p1 = v * pW[lane * 2 + 1];
    #pragma unroll
    for (int off = 32; off > 0; off >>= 1) {
        p0 += __shfl_down(p0, off);
        p1 += __shfl_down(p1, off);
    }
    if (lane == 0) {
        out[wave * 2 + 0] = p0 + pb[0];
        out[wave * 2 + 1] = p1 + pb[1];
    }
}

// ================= launch =================

extern "C" void kernel_launch(void* const* d_in, const int* in_sizes, int n_in,
                              void* d_out, int out_size, void* d_ws, size_t ws_size,
                              hipStream_t stream) {
    const float* node_feats = (const float*)d_in[0];
    const int*   etypes     = (const int*)d_in[1];
    const int*   src        = (const int*)d_in[2];
    const int*   dst        = (const int*)d_in[3];
    const int*   graph_ids  = (const int*)d_in[4];
    const float* W1 = (const float*)d_in[5];
    const float* b1 = (const float*)d_in[6];
    const float* W2 = (const float*)d_in[7];
    const float* b2 = (const float*)d_in[8];
    const float* W3 = (const float*)d_in[9];
    const float* b3 = (const float*)d_in[10];
    const float* fcW1 = (const float*)d_in[11];
    const float* fcb1 = (const float*)d_in[12];
    const float* fcW2 = (const float*)d_in[13];
    const float* fcb2 = (const float*)d_in[14];
    const float* fcW3 = (const float*)d_in[15];
    const float* fcb3 = (const float*)d_in[16];
    const float* pW = (const float*)d_in[17];
    const float* pb = (const float*)d_in[18];
    float* out = (float*)d_out;

    // workspace carve-up (256B aligned)
    char* p = (char*)d_ws;
    auto alloc = [&](size_t bytes) -> void* {
        void* r = (void*)p;
        p += (bytes + 255) & ~(size_t)255;
        return r;
    };
    int* blk_hist  = (int*)alloc((size_t)SORT_BLOCKS * N_RELS * sizeof(int));
    int* blk_off   = (int*)alloc((size_t)SORT_BLOCKS * N_RELS * sizeof(int));
    int* rel_ptr   = (int*)alloc((N_RELS + 1) * sizeof(int));
    int* rel_tot   = (int*)alloc(N_RELS * sizeof(int));
    int* tile_base = (int*)alloc((N_RELS + 1) * sizeof(int));
    unsigned long long* epk = (unsigned long long*)alloc((size_t)N_EDGES * sizeof(unsigned long long));
    int* src_s     = (int*)alloc((size_t)N_EDGES * sizeof(int));
    int* dpos      = (int*)alloc((size_t)N_EDGES * sizeof(int));
    int* cnt_d     = (int*)alloc((size_t)N_NODES * sizeof(int));
    int* outv      = (int*)alloc((size_t)N_NODES * sizeof(int));
    int* blk_tot   = (int*)alloc(NSCAN_BLKS * sizeof(int));
    int* blk_base  = (int*)alloc(NSCAN_BLKS * sizeof(int));
    int* cnt_g     = (int*)alloc(N_GRAPHS * sizeof(int));
    int* g_ptr     = (int*)alloc(N_GRAPHS * sizeof(int));
    int* done_flags= (int*)alloc(2 * sizeof(int));
    __hip_bfloat16* hb0 = (__hip_bfloat16*)alloc((size_t)N_NODES * DIM * sizeof(__hip_bfloat16));
    __hip_bfloat16* hb1 = (__hip_bfloat16*)alloc((size_t)N_NODES * DIM * sizeof(__hip_bfloat16));
    __hip_bfloat16* Wt1 = (__hip_bfloat16*)alloc((size_t)N_RELS * DIM * DIM * sizeof(__hip_bfloat16));
    __hip_bfloat16* Wt2 = (__hip_bfloat16*)alloc((size_t)N_RELS * DIM * DIM * sizeof(__hip_bfloat16));
    __hip_bfloat16* Wt3 = (__hip_bfloat16*)alloc((size_t)N_RELS * DIM * DIM * sizeof(__hip_bfloat16));
    __hip_bfloat16* msg = (__hip_bfloat16*)alloc((size_t)N_EDGES * DIM * sizeof(__hip_bfloat16));

    const int EBLK = (N_EDGES + 255) / 256;              // 3125
    const int AGG_BLOCKS = (N_NODES + 3) / 4;            // 12500

    // ---- prep (5 dispatches before layers) ----
    prep_kernel<<<SORT_BLOCKS, 256, 0, stream>>>(node_feats, etypes, hb0, cnt_d, blk_hist,
                                                 W1, W2, W3, Wt1, Wt2, Wt3, done_flags);
    relscan_kernel<<<N_RELS, 256, 0, stream>>>(blk_hist, blk_off, rel_tot,
                                               rel_ptr, tile_base, &done_flags[0]);
    scatter2_kernel<<<SORT_BLOCKS, 256, 0, stream>>>(etypes, src, dst, blk_hist, blk_off,
                                                     rel_ptr, epk, cnt_d);
    scanblk_kernel<<<NSCAN_BLKS, SCAN_BLK, 0, stream>>>(cnt_d, outv, blk_tot, blk_base,
                                                        graph_ids, g_ptr, cnt_g,
                                                        &done_flags[1]);
    unpack_kernel<<<EBLK, 256, 0, stream>>>(epk, outv, blk_base, src_s, dpos);

    // ---- 3 RGCN layers ----
    msg_mfma_kernel<<<MSG_BLOCKS, 256, 0, stream>>>(hb0, Wt1, rel_ptr, tile_base,
                                                    src_s, dpos, msg);
    agg_kernel<<<AGG_BLOCKS, 256, 0, stream>>>(msg, outv, blk_base, cnt_d, b1, hb1);

    msg_mfma_kernel<<<MSG_BLOCKS, 256, 0, stream>>>(hb1, Wt2, rel_ptr, tile_base,
                                                    src_s, dpos, msg);
    agg_kernel<<<AGG_BLOCKS, 256, 0, stream>>>(msg, outv, blk_base, cnt_d, b2, hb0);

    msg_mfma_kernel<<<MSG_BLOCKS, 256, 0, stream>>>(hb0, Wt3, rel_ptr, tile_base,
                                                    src_s, dpos, msg);
    agg_kernel<<<AGG_BLOCKS, 256, 0, stream>>>(msg, outv, blk_base, cnt_d, b3, hb1);

    // ---- fused pool + FC head ----
    poolfc_kernel<<<(N_GRAPHS + 3) / 4, 256, 0, stream>>>(hb1, g_ptr, cnt_g,
                                                          fcW1, fcb1, fcW2, fcb2,
                                                          fcW3, fcb3, pW, pb, out);
}

// Round 11
// 369.051 us; speedup vs baseline: 3.3666x; 1.0286x over previous
//
#include <hip/hip_runtime.h>
#include <hip/hip_bf16.h>

#define N_NODES 50000
#define N_EDGES 800000
#define N_RELS 65
#define DIM 64
#define N_GRAPHS 512

// dst-chunk sort geometry
#define DCH 512                                   // nodes per dst-chunk
#define NCH 98                                    // ceil(50000/512)
#define SB3 256                                   // scatterc blocks
#define EC3 3125                                  // edges per scatterc block (256*3125 = 800000)

#define MSG_BLOCKS 2048
#define NWAVES (MSG_BLOCKS * 4)

typedef __attribute__((ext_vector_type(8))) short short8;
typedef __attribute__((ext_vector_type(4))) float f32x4;

// ================= K1 prep: h-convert + W transpose + per-block dst-chunk hist =================

__global__ __launch_bounds__(256) void prep_kernel(
    const float* __restrict__ x, const int* __restrict__ dst,
    __hip_bfloat16* __restrict__ y, int* __restrict__ blk_hist3,
    const float* __restrict__ W1, const float* __restrict__ W2,
    const float* __restrict__ W3,
    __hip_bfloat16* __restrict__ Wt1, __hip_bfloat16* __restrict__ Wt2,
    __hip_bfloat16* __restrict__ Wt3,
    int* __restrict__ done_flags) {
    __shared__ int chist[128];
    __shared__ float tile[64][65];
    int t = threadIdx.x, b = blockIdx.x;
    int gtid = b * 256 + t;

    if (gtid < 2) done_flags[gtid] = 0;

    // blocks 0..255: dst-chunk histogram of their 3125-edge slice
    if (b < SB3) {
        if (t < 128) chist[t] = 0;
        __syncthreads();
        int lo = b * EC3;
        #pragma unroll
        for (int k = 0; k < 13; ++k) {
            int i = lo + t + k * 256;
            if (i < lo + EC3) atomicAdd(&chist[dst[i] >> 9], 1);
        }
    }

    // grid-stride h conversion (f32 -> bf16, vectorized)
    for (int i = gtid; i < (N_NODES * DIM) / 4; i += 1024 * 256) {
        float4 v = *(const float4*)(x + (size_t)i * 4);
        unsigned short us[4];
        us[0] = __hip_bfloat16_raw(__float2bfloat16(v.x)).x;
        us[1] = __hip_bfloat16_raw(__float2bfloat16(v.y)).x;
        us[2] = __hip_bfloat16_raw(__float2bfloat16(v.z)).x;
        us[3] = __hip_bfloat16_raw(__float2bfloat16(v.w)).x;
        *(ushort4*)(y + (size_t)i * 4) = *(const ushort4*)us;
    }

    // W transpose+convert: blocks 256..450 (LDS-tiled, coalesced both sides)
    if (b >= SB3 && b < SB3 + 3 * N_RELS) {
        int bb = b - SB3;
        int which = bb / N_RELS, r = bb - which * N_RELS;
        const float* W = (which == 0) ? W1 : (which == 1) ? W2 : W3;
        __hip_bfloat16* Wt = (which == 0) ? Wt1 : (which == 1) ? Wt2 : Wt3;
        for (int i = t; i < 4096; i += 256) {
            int row = i >> 6, col = i & 63;
            tile[row][col] = W[(size_t)r * 4096 + i];
        }
        __syncthreads();
        for (int i = t; i < 4096; i += 256) {
            int row = i >> 6, col = i & 63;
            Wt[(size_t)r * 4096 + i] = __float2bfloat16(tile[col][row]);
        }
    }

    if (b < SB3) {
        __syncthreads();
        if (t < NCH) blk_hist3[t * SB3 + b] = chist[t];
    }
}

// ================= K2 chunkscan: per-chunk block offsets; last block: chunk_ptr + g_ptr =================

__global__ __launch_bounds__(256) void chunkscan_kernel(
    const int* __restrict__ blk_hist3, int* __restrict__ blk_off3,
    int* __restrict__ chunk_tot, int* __restrict__ chunk_ptr,
    const int* __restrict__ gid, int* __restrict__ g_ptr, int* __restrict__ cnt_g,
    int* __restrict__ done) {
    __shared__ int wsum[4];
    __shared__ int is_last;
    int r = blockIdx.x, t = threadIdx.x;
    int w = t >> 6, lane = t & 63;

    int v = blk_hist3[r * SB3 + t];
    int x = v;
    #pragma unroll
    for (int off = 1; off < 64; off <<= 1) {
        int y = __shfl_up(x, off);
        if (lane >= off) x += y;
    }
    if (lane == 63) wsum[w] = x;
    __syncthreads();
    int base = 0;
    for (int i = 0; i < w; ++i) base += wsum[i];
    blk_off3[r * SB3 + t] = base + x - v;

    if (t == 255) {
        __hip_atomic_store(&chunk_tot[r], base + x, __ATOMIC_RELAXED,
                           __HIP_MEMORY_SCOPE_AGENT);
        __threadfence();
        int ticket = atomicAdd(done, 1);
        is_last = (ticket == NCH - 1) ? 1 : 0;
    }
    __syncthreads();

    if (is_last) {
        if (t == 0) {
            int run = 0;
            for (int q = 0; q < NCH; ++q) {
                int vv = __hip_atomic_load(&chunk_tot[q], __ATOMIC_RELAXED,
                                           __HIP_MEMORY_SCOPE_AGENT);
                chunk_ptr[q] = run; run += vv;
            }
            chunk_ptr[NCH] = run;   // == N_EDGES
        }
        // graph segments via binary search (graph_ids sorted)
        for (int g = t; g < N_GRAPHS; g += 256) {
            int lo2 = 0, hi2 = N_NODES;
            while (lo2 < hi2) { int m = (lo2 + hi2) >> 1; if (gid[m] < g) lo2 = m + 1; else hi2 = m; }
            int a2 = lo2;
            lo2 = 0; hi2 = N_NODES;
            int g1 = g + 1;
            while (lo2 < hi2) { int m = (lo2 + hi2) >> 1; if (gid[m] < g1) lo2 = m + 1; else hi2 = m; }
            g_ptr[g] = a2;
            cnt_g[g] = lo2 - a2;
        }
    }
}

// ================= K3 scatterc: LDS-staged counting sort by dst-chunk (no global atomics) =========
// rec: src(16) | dl(9)<<16 | rel(7)<<25

__global__ __launch_bounds__(256) void scatterc_kernel(
    const int* __restrict__ et, const int* __restrict__ src,
    const int* __restrict__ dst, const int* __restrict__ blk_hist3,
    const int* __restrict__ blk_off3, const int* __restrict__ chunk_ptr,
    unsigned* __restrict__ epk2) {
    __shared__ unsigned srec[EC3];
    __shared__ unsigned char sbin[EC3];
    __shared__ int loff[NCH], lcur[NCH], gbase[NCH];
    __shared__ int wsum[4];
    int t = threadIdx.x, b = blockIdx.x;
    int w = t >> 6, lane = t & 63;

    int v = (t < NCH) ? blk_hist3[t * SB3 + b] : 0;
    int x = v;
    #pragma unroll
    for (int off = 1; off < 64; off <<= 1) {
        int y = __shfl_up(x, off);
        if (lane >= off) x += y;
    }
    if (lane == 63) wsum[w] = x;
    __syncthreads();
    int base = 0;
    for (int i = 0; i < w; ++i) base += wsum[i];
    if (t < NCH) {
        int pref = base + x - v;
        loff[t] = pref;
        lcur[t] = pref;
        gbase[t] = chunk_ptr[t] + blk_off3[t * SB3 + b];
    }
    __syncthreads();

    int lo = b * EC3;
    #pragma unroll
    for (int k = 0; k < 13; ++k) {
        int i = lo + t + k * 256;
        if (i < lo + EC3) {
            int d = dst[i];
            int bin = d >> 9;
            unsigned rec = (unsigned)src[i] | ((unsigned)(d & 511) << 16) |
                           ((unsigned)et[i] << 25);
            int pl = atomicAdd(&lcur[bin], 1);
            srec[pl] = rec;
            sbin[pl] = (unsigned char)bin;
        }
    }
    __syncthreads();

    #pragma unroll
    for (int k = 0; k < 13; ++k) {
        int i = t + k * 256;
        if (i < EC3) {
            int bin = sbin[i];
            epk2[gbase[bin] + i - loff[bin]] = srec[i];
        }
    }
}

// ================= K4 chunksort: per-chunk 512-bin dl sort -> dst-sorted records +
//                   row_ptr/cnt_d + per-chunk rel histograms =================
// efin2[pos] = src(16) | rel(7)<<16 ; pos is the edge's global dst-sorted index (= dpos)

__global__ __launch_bounds__(256) void chunksort_kernel(
    const unsigned* __restrict__ epk2, const int* __restrict__ chunk_ptr,
    unsigned* __restrict__ efin2, int* __restrict__ cnt_d,
    int* __restrict__ row_ptr, int* __restrict__ relh_g) {
    __shared__ int h512[DCH], off512[DCH], cur512[DCH];
    __shared__ int relh[N_RELS];
    __shared__ int wsum[4];
    int c = blockIdx.x, t = threadIdx.x;
    int w = t >> 6, lane = t & 63;
    int e0 = chunk_ptr[c], e1 = chunk_ptr[c + 1];
    int n = e1 - e0;

    h512[2 * t] = 0; h512[2 * t + 1] = 0;
    if (t < N_RELS) relh[t] = 0;
    __syncthreads();

    for (int i = t; i < n; i += 256) {
        unsigned v = epk2[e0 + i];            // L2-cold once; re-read below is L2-hot
        atomicAdd(&h512[(v >> 16) & 511], 1);
        atomicAdd(&relh[v >> 25], 1);
    }
    __syncthreads();

    int v0 = h512[2 * t], v1 = h512[2 * t + 1];
    int s = v0 + v1;
    int x = s;
    #pragma unroll
    for (int off = 1; off < 64; off <<= 1) {
        int y = __shfl_up(x, off);
        if (lane >= off) x += y;
    }
    if (lane == 63) wsum[w] = x;
    __syncthreads();
    int base = 0;
    for (int i = 0; i < w; ++i) base += wsum[i];
    int run = base + x - s;
    off512[2 * t] = run;
    off512[2 * t + 1] = run + v0;
    cur512[2 * t] = run;
    cur512[2 * t + 1] = run + v0;
    __syncthreads();   // R10 FIX: off512[j] below is read cross-thread (j=t, t+256
                       // written by threads t/2, t/2+128); missing barrier was the
                       // R9 crash (garbage row_ptr -> OOB reads in agg).

    // CSR for agg falls out of the sort for free
    #pragma unroll
    for (int j = t; j < DCH; j += 256) {
        int d = c * DCH + j;
        if (d < N_NODES) { cnt_d[d] = h512[j]; row_ptr[d] = e0 + off512[j]; }
    }
    if (t < N_RELS) relh_g[t * NCH + c] = relh[t];
    __syncthreads();

    for (int i = t; i < n; i += 256) {
        unsigned v = epk2[e0 + i];
        int dl = (v >> 16) & 511;
        int pos = atomicAdd(&cur512[dl], 1);
        // scattered u32 writes within a 32KB window: L2 absorbs
        efin2[e0 + pos] = (v & 0xFFFFu) | ((v >> 25) << 16);
    }
}

// ================= K5 relscan: scan per-chunk rel hists; last block does reltop =================

__global__ __launch_bounds__(128) void relscan_kernel(
    const int* __restrict__ relh_g, int* __restrict__ blk_off_rel,
    int* __restrict__ rel_tot, int* __restrict__ rel_ptr,
    int* __restrict__ tile_base, int* __restrict__ done) {
    __shared__ int wsum2[2];
    int r = blockIdx.x, t = threadIdx.x;
    int w = t >> 6, lane = t & 63;
    int v = (t < NCH) ? relh_g[r * NCH + t] : 0;
    int x = v;
    #pragma unroll
    for (int off = 1; off < 64; off <<= 1) {
        int y = __shfl_up(x, off);
        if (lane >= off) x += y;
    }
    if (lane == 63) wsum2[w] = x;
    __syncthreads();
    int base = (w == 1) ? wsum2[0] : 0;
    if (t < NCH) blk_off_rel[r * NCH + t] = base + x - v;

    if (t == 127) {
        int tot = wsum2[0] + wsum2[1];
        __hip_atomic_store(&rel_tot[r], tot, __ATOMIC_RELAXED, __HIP_MEMORY_SCOPE_AGENT);
        __threadfence();
        int ticket = atomicAdd(done, 1);
        if (ticket == N_RELS - 1) {
            int ss = 0, tt = 0;
            for (int q = 0; q < N_RELS; ++q) {
                int vv = __hip_atomic_load(&rel_tot[q], __ATOMIC_RELAXED,
                                           __HIP_MEMORY_SCOPE_AGENT);
                rel_ptr[q] = ss; ss += vv;
                tile_base[q] = tt; tt += (vv + 15) >> 4;
            }
            rel_ptr[N_RELS] = N_EDGES;
            tile_base[N_RELS] = tt;
        }
    }
}

// ================= K6 relscatter: chunk-aligned rel sort -> final (src, dpos) records ============
// epk3[p] = src(16) | dpos<<32 ; writes land in ~1KB runs per (chunk,rel), L2 absorbs

__global__ __launch_bounds__(256) void relscatter_kernel(
    const unsigned* __restrict__ efin2, const int* __restrict__ chunk_ptr,
    const int* __restrict__ rel_ptr, const int* __restrict__ blk_off_rel,
    unsigned long long* __restrict__ epk3) {
    __shared__ int lcur[N_RELS];
    int c = blockIdx.x, t = threadIdx.x;
    int e0 = chunk_ptr[c], n = chunk_ptr[c + 1] - e0;
    if (t < N_RELS) lcur[t] = rel_ptr[t] + blk_off_rel[t * NCH + c];
    __syncthreads();
    for (int i = t; i < n; i += 256) {
        unsigned v = efin2[e0 + i];
        int rel = v >> 16;
        int pos = atomicAdd(&lcur[rel], 1);
        epk3[pos] = (unsigned long long)(v & 0xFFFFu) |
                    ((unsigned long long)(unsigned)(e0 + i) << 32);
    }
}

// ================= phase 1: MFMA message kernel — zero-LDS, 4-col-interleaved B (R5-exact) =======

__device__ inline unsigned pack2bf(float x, float y) {
    unsigned short ux = __hip_bfloat16_raw(__float2bfloat16(x)).x;
    unsigned short uy = __hip_bfloat16_raw(__float2bfloat16(y)).x;
    return (unsigned)ux | ((unsigned)uy << 16);
}

__global__ __launch_bounds__(256) void msg_mfma_kernel(
    const __hip_bfloat16* __restrict__ hb, const __hip_bfloat16* __restrict__ Wt,
    const int* __restrict__ rel_ptr, const int* __restrict__ tile_base,
    const unsigned long long* __restrict__ epk3,
    __hip_bfloat16* __restrict__ msg) {
    int t = threadIdx.x;
    int w = t >> 6, lane = t & 63;
    int quad = lane >> 4, m16 = lane & 15;
    int wave = blockIdx.x * 4 + w;

    int ntiles = tile_base[N_RELS];
    int tpw = (ntiles + NWAVES - 1) / NWAVES;
    int T = wave * tpw;
    int T1 = T + tpw; if (T1 > ntiles) T1 = ntiles;
    if (T >= T1) return;

    int r = 0;
    while (T >= tile_base[r + 1]) ++r;

    while (T < T1) {
        int chunk_end = tile_base[r + 1]; if (chunk_end > T1) chunk_end = T1;
        int e_base = rel_ptr[r], t_base = tile_base[r];
        int seg_end = rel_ptr[r + 1];

        const __hip_bfloat16* Wr = Wt + (size_t)r * (DIM * DIM);
        short8 bf00 = *(const short8*)(Wr + (4 * m16)     * DIM + quad * 8);
        short8 bf01 = *(const short8*)(Wr + (4 * m16 + 1) * DIM + quad * 8);
        short8 bf02 = *(const short8*)(Wr + (4 * m16 + 2) * DIM + quad * 8);
        short8 bf03 = *(const short8*)(Wr + (4 * m16 + 3) * DIM + quad * 8);
        short8 bf10 = *(const short8*)(Wr + (4 * m16)     * DIM + 32 + quad * 8);
        short8 bf11 = *(const short8*)(Wr + (4 * m16 + 1) * DIM + 32 + quad * 8);
        short8 bf12 = *(const short8*)(Wr + (4 * m16 + 2) * DIM + 32 + quad * 8);
        short8 bf13 = *(const short8*)(Wr + (4 * m16 + 3) * DIM + 32 + quad * 8);

        // final (src, dpos) precomputed by the sort — single 8B load, no dependent lookups
        auto loadidx = [&](int TT, int& sv, int& dp) {
            int TC = TT < chunk_end ? TT : chunk_end - 1;
            int i = e_base + (TC - t_base) * 16 + lane;
            if (i >= N_EDGES) i = N_EDGES - 1;
            unsigned long long e = epk3[i];
            sv = (int)(e & 0xFFFFu);
            dp = (int)(e >> 32);
        };
        auto gatherA = [&](int sv, short8& x0, short8& x1) {
            int s = __shfl(sv, m16);
            const __hip_bfloat16* hp = hb + (size_t)s * DIM + quad * 8;
            x0 = *(const short8*)hp;
            x1 = *(const short8*)(hp + 32);
        };

        int sv0, dp0, sv1, dp1, sv2, dp2;
        short8 a0c, a1c, a0n, a1n;
        loadidx(T,     sv0, dp0);
        loadidx(T + 1, sv1, dp1);
        gatherA(sv0, a0c, a1c);

        for (; T < chunk_end; ++T) {
            loadidx(T + 2, sv2, dp2);
            gatherA(sv1, a0n, a1n);

            int e0 = e_base + (T - t_base) * 16;
            int rows = seg_end - e0; if (rows > 16) rows = 16;

            f32x4 c0 = {0.f, 0.f, 0.f, 0.f}, c1 = c0, c2 = c0, c3 = c0;
            c0 = __builtin_amdgcn_mfma_f32_16x16x32_bf16(a0c, bf00, c0, 0, 0, 0);
            c1 = __builtin_amdgcn_mfma_f32_16x16x32_bf16(a0c, bf01, c1, 0, 0, 0);
            c2 = __builtin_amdgcn_mfma_f32_16x16x32_bf16(a0c, bf02, c2, 0, 0, 0);
            c3 = __builtin_amdgcn_mfma_f32_16x16x32_bf16(a0c, bf03, c3, 0, 0, 0);
            c0 = __builtin_amdgcn_mfma_f32_16x16x32_bf16(a1c, bf10, c0, 0, 0, 0);
            c1 = __builtin_amdgcn_mfma_f32_16x16x32_bf16(a1c, bf11, c1, 0, 0, 0);
            c2 = __builtin_amdgcn_mfma_f32_16x16x32_bf16(a1c, bf12, c2, 0, 0, 0);
            c3 = __builtin_amdgcn_mfma_f32_16x16x32_bf16(a1c, bf13, c3, 0, 0, 0);

            int dpr[4];
            #pragma unroll
            for (int g = 0; g < 4; ++g) dpr[g] = __shfl(dp0, quad * 4 + g);

            #pragma unroll
            for (int g = 0; g < 4; ++g) {
                if (quad * 4 + g < rows) {
                    uint2 pk;
                    pk.x = pack2bf(c0[g], c1[g]);
                    pk.y = pack2bf(c2[g], c3[g]);
                    *(uint2*)(msg + (size_t)dpr[g] * DIM + 4 * m16) = pk;
                }
            }

            sv0 = sv1; dp0 = dp1; sv1 = sv2; dp1 = dp2;
            a0c = a0n; a1c = a1n;
        }
        ++r;
        while (T < T1 && T >= tile_base[r + 1]) ++r;
    }
}

// ================= phase 2: vectorized pull-aggregate + bias + ReLU (R5-exact) =================

__global__ __launch_bounds__(256) void agg_kernel(
    const __hip_bfloat16* __restrict__ msg, const int* __restrict__ row_ptr,
    const int* __restrict__ cnt_d, const float* __restrict__ b,
    __hip_bfloat16* __restrict__ hout) {
    int wave = blockIdx.x * 4 + (threadIdx.x >> 6);
    int lane = threadIdx.x & 63;
    if (wave >= N_NODES) return;
    int j0 = row_ptr[wave];
    int n  = cnt_d[wave];
    int rgrp = lane >> 3, dgrp = lane & 7;

    float a[8] = {0.f, 0.f, 0.f, 0.f, 0.f, 0.f, 0.f, 0.f};
    for (int jj = 0; jj < n; jj += 8) {
        int row = jj + rgrp;
        if (row < n) {
            uint4 d = *(const uint4*)(msg + (size_t)(j0 + row) * DIM + dgrp * 8);
            a[0] += __uint_as_float(d.x << 16);
            a[1] += __uint_as_float(d.x & 0xffff0000u);
            a[2] += __uint_as_float(d.y << 16);
            a[3] += __uint_as_float(d.y & 0xffff0000u);
            a[4] += __uint_as_float(d.z << 16);
            a[5] += __uint_as_float(d.z & 0xffff0000u);
            a[6] += __uint_as_float(d.w << 16);
            a[7] += __uint_as_float(d.w & 0xffff0000u);
        }
    }
    #pragma unroll
    for (int i = 0; i < 8; ++i) {
        a[i] += __shfl_xor(a[i], 8);
        a[i] += __shfl_xor(a[i], 16);
        a[i] += __shfl_xor(a[i], 32);
    }
    if (rgrp == 0) {
        unsigned short us[8];
        #pragma unroll
        for (int i = 0; i < 8; ++i) {
            float v = a[i] + b[dgrp * 8 + i];
            us[i] = __hip_bfloat16_raw(__float2bfloat16(v > 0.f ? v : 0.f)).x;
        }
        *(uint4*)(hout + (size_t)wave * DIM + dgrp * 8) = *(const uint4*)us;
    }
}

// ================= fused pool + FC x3 + prediction head =================

__global__ __launch_bounds__(256) void poolfc_kernel(
    const __hip_bfloat16* __restrict__ h, const int* __restrict__ g_ptr,
    const int* __restrict__ cnt_g,
    const float* __restrict__ W1, const float* __restrict__ b1,
    const float* __restrict__ W2, const float* __restrict__ b2,
    const float* __restrict__ W3, const float* __restrict__ b3,
    const float* __restrict__ pW, const float* __restrict__ pb,
    float* __restrict__ out) {
    int wave = blockIdx.x * 4 + (threadIdx.x >> 6);
    int lane = threadIdx.x & 63;
    if (wave >= N_GRAPHS) return;
    int j0 = g_ptr[wave];
    int n  = cnt_g[wave];
    int rgrp = lane >> 3, dgrp = lane & 7;

    float a[8] = {0.f, 0.f, 0.f, 0.f, 0.f, 0.f, 0.f, 0.f};
    for (int jj = 0; jj < n; jj += 8) {
        int row = jj + rgrp;
        if (row < n) {
            uint4 d = *(const uint4*)(h + (size_t)(j0 + row) * DIM + dgrp * 8);
            a[0] += __uint_as_float(d.x << 16);
            a[1] += __uint_as_float(d.x & 0xffff0000u);
            a[2] += __uint_as_float(d.y << 16);
            a[3] += __uint_as_float(d.y & 0xffff0000u);
            a[4] += __uint_as_float(d.z << 16);
            a[5] += __uint_as_float(d.z & 0xffff0000u);
            a[6] += __uint_as_float(d.w << 16);
            a[7] += __uint_as_float(d.w & 0xffff0000u);
        }
    }
    #pragma unroll
    for (int i = 0; i < 8; ++i) {
        a[i] += __shfl_xor(a[i], 8);
        a[i] += __shfl_xor(a[i], 16);
        a[i] += __shfl_xor(a[i], 32);
    }
    float v;
    {
        float acc = b1[lane];
        #pragma unroll
        for (int o = 0; o < 8; ++o)
            #pragma unroll
            for (int q = 0; q < 8; ++q)
                acc += __shfl(a[o], q) * W1[(q * 8 + o) * DIM + lane];
        v = acc > 0.f ? acc : 0.f;
    }
    {
        float acc = b2[lane];
        #pragma unroll
        for (int d = 0; d < DIM; ++d)
            acc += __shfl(v, d) * W2[d * DIM + lane];
        v = acc > 0.f ? acc : 0.f;
    }
    {
        float acc = b3[lane];
        #pragma unroll
        for (int d = 0; d < DIM; ++d)
            acc += __shfl(v, d) * W3[d * DIM + lane];
        v = acc > 0.f ? acc : 0.f;
    }
    float p0 = v * pW[lane * 2 + 0];
    float p1 = v * pW[lane * 2 + 1];
    #pragma unroll
    for (int off = 32; off > 0; off >>= 1) {
        p0 += __shfl_down(p0, off);
        p1 += __shfl_down(p1, off);
    }
    if (lane == 0) {
        out[wave * 2 + 0] = p0 + pb[0];
        out[wave * 2 + 1] = p1 + pb[1];
    }
}

// ================= launch =================

extern "C" void kernel_launch(void* const* d_in, const int* in_sizes, int n_in,
                              void* d_out, int out_size, void* d_ws, size_t ws_size,
                              hipStream_t stream) {
    const float* node_feats = (const float*)d_in[0];
    const int*   etypes     = (const int*)d_in[1];
    const int*   src        = (const int*)d_in[2];
    const int*   dst        = (const int*)d_in[3];
    const int*   graph_ids  = (const int*)d_in[4];
    const float* W1 = (const float*)d_in[5];
    const float* b1 = (const float*)d_in[6];
    const float* W2 = (const float*)d_in[7];
    const float* b2 = (const float*)d_in[8];
    const float* W3 = (const float*)d_in[9];
    const float* b3 = (const float*)d_in[10];
    const float* fcW1 = (const float*)d_in[11];
    const float* fcb1 = (const float*)d_in[12];
    const float* fcW2 = (const float*)d_in[13];
    const float* fcb2 = (const float*)d_in[14];
    const float* fcW3 = (const float*)d_in[15];
    const float* fcb3 = (const float*)d_in[16];
    const float* pW = (const float*)d_in[17];
    const float* pb = (const float*)d_in[18];
    float* out = (float*)d_out;

    // workspace carve-up (256B aligned)
    char* p = (char*)d_ws;
    auto alloc = [&](size_t bytes) -> void* {
        void* r = (void*)p;
        p += (bytes + 255) & ~(size_t)255;
        return r;
    };
    int* blk_hist3  = (int*)alloc((size_t)NCH * SB3 * sizeof(int));
    int* blk_off3   = (int*)alloc((size_t)NCH * SB3 * sizeof(int));
    int* chunk_tot  = (int*)alloc(NCH * sizeof(int));
    int* chunk_ptr  = (int*)alloc((NCH + 1) * sizeof(int));
    unsigned* epk2  = (unsigned*)alloc((size_t)N_EDGES * sizeof(unsigned));
    unsigned* efin2 = (unsigned*)alloc((size_t)N_EDGES * sizeof(unsigned));
    unsigned long long* epk3 = (unsigned long long*)alloc((size_t)N_EDGES * sizeof(unsigned long long));
    int* relh_g     = (int*)alloc((size_t)N_RELS * NCH * sizeof(int));
    int* blk_off_rel= (int*)alloc((size_t)N_RELS * NCH * sizeof(int));
    int* rel_tot    = (int*)alloc(N_RELS * sizeof(int));
    int* rel_ptr    = (int*)alloc((N_RELS + 1) * sizeof(int));
    int* tile_base  = (int*)alloc((N_RELS + 1) * sizeof(int));
    int* cnt_d      = (int*)alloc((size_t)N_NODES * sizeof(int));
    int* row_ptr    = (int*)alloc((size_t)N_NODES * sizeof(int));
    int* cnt_g      = (int*)alloc(N_GRAPHS * sizeof(int));
    int* g_ptr      = (int*)alloc(N_GRAPHS * sizeof(int));
    int* done_flags = (int*)alloc(2 * sizeof(int));
    __hip_bfloat16* hb0 = (__hip_bfloat16*)alloc((size_t)N_NODES * DIM * sizeof(__hip_bfloat16));
    __hip_bfloat16* hb1 = (__hip_bfloat16*)alloc((size_t)N_NODES * DIM * sizeof(__hip_bfloat16));
    __hip_bfloat16* Wt1 = (__hip_bfloat16*)alloc((size_t)N_RELS * DIM * DIM * sizeof(__hip_bfloat16));
    __hip_bfloat16* Wt2 = (__hip_bfloat16*)alloc((size_t)N_RELS * DIM * DIM * sizeof(__hip_bfloat16));
    __hip_bfloat16* Wt3 = (__hip_bfloat16*)alloc((size_t)N_RELS * DIM * DIM * sizeof(__hip_bfloat16));
    __hip_bfloat16* msg = (__hip_bfloat16*)alloc((size_t)N_EDGES * DIM * sizeof(__hip_bfloat16));

    const int AGG_BLOCKS = (N_NODES + 3) / 4;            // 12500

    // ---- prep: atomic-free two-level sort (6 dispatches) ----
    prep_kernel<<<1024, 256, 0, stream>>>(node_feats, dst, hb0, blk_hist3,
                                          W1, W2, W3, Wt1, Wt2, Wt3, done_flags);
    chunkscan_kernel<<<NCH, 256, 0, stream>>>(blk_hist3, blk_off3, chunk_tot, chunk_ptr,
                                              graph_ids, g_ptr, cnt_g, &done_flags[0]);
    scatterc_kernel<<<SB3, 256, 0, stream>>>(etypes, src, dst, blk_hist3, blk_off3,
                                             chunk_ptr, epk2);
    chunksort_kernel<<<NCH, 256, 0, stream>>>(epk2, chunk_ptr, efin2, cnt_d,
                                              row_ptr, relh_g);
    relscan_kernel<<<N_RELS, 128, 0, stream>>>(relh_g, blk_off_rel, rel_tot,
                                               rel_ptr, tile_base, &done_flags[1]);
    relscatter_kernel<<<NCH, 256, 0, stream>>>(efin2, chunk_ptr, rel_ptr,
                                               blk_off_rel, epk3);

    // ---- 3 RGCN layers ----
    msg_mfma_kernel<<<MSG_BLOCKS, 256, 0, stream>>>(hb0, Wt1, rel_ptr, tile_base,
                                                    epk3, msg);
    agg_kernel<<<AGG_BLOCKS, 256, 0, stream>>>(msg, row_ptr, cnt_d, b1, hb1);

    msg_mfma_kernel<<<MSG_BLOCKS, 256, 0, stream>>>(hb1, Wt2, rel_ptr, tile_base,
                                                    epk3, msg);
    agg_kernel<<<AGG_BLOCKS, 256, 0, stream>>>(msg, row_ptr, cnt_d, b2, hb0);

    msg_mfma_kernel<<<MSG_BLOCKS, 256, 0, stream>>>(hb0, Wt3, rel_ptr, tile_base,
                                                    epk3, msg);
    agg_kernel<<<AGG_BLOCKS, 256, 0, stream>>>(msg, row_ptr, cnt_d, b3, hb1);

    // ---- fused pool + FC head ----
    poolfc_kernel<<<(N_GRAPHS + 3) / 4, 256, 0, stream>>>(hb1, g_ptr, cnt_g,
                                                          fcW1, fcb1, fcW2, fcb2,
                                                          fcW3, fcb3, pW, pb, out);
}